// Round 9
// baseline (3003.130 us; speedup 1.0000x reference)
//
#include <hip/hip_runtime.h>
#include <math.h>

#define NLAYER 6
#define DMODEL 1024
#define NHEAD  16
#define DFFN   4096
#define VOCAB  32000
#define NBATCH 4
#define SEQLEN 512
#define HDIM   64
#define MROWS  (NBATCH*SEQLEN)
#define MiB    (1024L*1024L)

typedef __attribute__((ext_vector_type(8))) short bf16x8;
typedef __attribute__((ext_vector_type(4))) float f32x4;
typedef unsigned short u16;

__device__ __forceinline__ float waveSum(float v) {
#pragma unroll
  for (int off = 32; off > 0; off >>= 1) v += __shfl_xor(v, off);
  return v;
}
__device__ __forceinline__ u16 f2bf(float x) {
  unsigned u = __float_as_uint(x);
  u += 0x7FFFu + ((u >> 16) & 1u);   // RNE
  return (u16)(u >> 16);
}
__device__ __forceinline__ float bf2f(u16 h) {
  return __uint_as_float((unsigned)h << 16);
}
__device__ __forceinline__ void load_lds16(const u16* src, u16* dst) {
  __builtin_amdgcn_global_load_lds(
      (const __attribute__((address_space(1))) unsigned int*)src,
      (__attribute__((address_space(3))) unsigned int*)dst, 16, 0, 0);
}

// Tiled bf16 layout: tile(rb,kc) of a [R][K] matrix = 16 rows x 32 K (1 KiB).
// base = (rb*(K/32)+kc)*512 ; elem(row,k) = ((k>>3)&3)*128 + (row&15)*8 + (k&7)

// ---- embedding gather + fp32 out + tiled hi ----
__global__ __launch_bounds__(256) void embed_t_kernel(
    const int* __restrict__ tok, const float* __restrict__ emb,
    float* __restrict__ out, u16* __restrict__ th)
{
  const long row = blockIdx.x;
  const int t = tok[row];
  const int k0 = threadIdx.x * 4;
  const float4 v = *(const float4*)(emb + (long)t * DMODEL + k0);
  *(float4*)(out + row * DMODEL + k0) = v;
  const long off = ((row >> 4) * 32 + (k0 >> 5)) * 512 +
                   (long)(((k0 & 31) >> 3)) * 128 + (row & 15) * 8 + (k0 & 7);
  uint2 uh;
  uh.x = (unsigned)f2bf(v.x) | ((unsigned)f2bf(v.y) << 16);
  uh.y = (unsigned)f2bf(v.z) | ((unsigned)f2bf(v.w) << 16);
  *(uint2*)(th + off) = uh;
}

// ---- rope tables ----
__global__ __launch_bounds__(256) void rope_tab_kernel(float* __restrict__ cosT, float* __restrict__ sinT)
{
  const int idx = blockIdx.x * 256 + threadIdx.x;   // < SEQLEN*32
  const int s = idx >> 5, i = idx & 31;
  const float e = (float)(2 * i) / 64.0f;
  const float inv = 1.0f / powf(10000.0f, e);
  const float ang = (float)s * inv;
  cosT[idx] = cosf(ang);
  sinT[idx] = sinf(ang);
}

// ---- generic weight convert: W[K][ldN] fp32 slice -> tiled bf16 hi ----
__global__ __launch_bounds__(256) void wconv_kernel(
    const float* __restrict__ W, u16* __restrict__ Wh,
    int K, int ldN, int nbase)
{
  __shared__ float tile[32][68];
  const int t = threadIdx.x;
  const int k0 = blockIdx.x * 32, n0 = blockIdx.y * 64;
  {
    const int r = t >> 3, c = (t & 7) * 8;
    const float* wp = W + (long)(k0 + r) * ldN + nbase + n0 + c;
    *(float4*)&tile[r][c]     = *(const float4*)wp;
    *(float4*)&tile[r][c + 4] = *(const float4*)(wp + 4);
  }
  __syncthreads();
  const int fr = t & 15, kg = (t >> 4) & 3, nb = t >> 6;
  const int n = nb * 16 + fr;
  unsigned ph[4];
#pragma unroll
  for (int i = 0; i < 4; ++i) {
    const float x0 = tile[kg * 8 + 2 * i][n];
    const float x1 = tile[kg * 8 + 2 * i + 1][n];
    ph[i] = (unsigned)f2bf(x0) | ((unsigned)f2bf(x1) << 16);
  }
  const int tk = K >> 5;
  const long off = ((long)(n0 / 16 + nb) * tk + (k0 >> 5)) * 512 + kg * 128 + fr * 8;
  *(uint4*)(Wh + off) = make_uint4(ph[0], ph[1], ph[2], ph[3]);
}

// ---- FFN weight convert: W1 and W2 -> tiled hi, single launch ----
__global__ __launch_bounds__(256) void wconv_ffn_kernel(
    const float* __restrict__ W1, const float* __restrict__ W2,
    u16* __restrict__ f1h, u16* __restrict__ f2h)
{
  __shared__ float tile[32][68];
  const int bx = blockIdx.x, t = threadIdx.x;
  const float* W; u16* out; int K, ldN, k0, n0;
  if (bx < 2048) { W = W1; out = f1h; K = 1024; ldN = 4096; k0 = (bx & 31) * 32;  n0 = (bx >> 5) * 64; }
  else { const int xx = bx - 2048; W = W2; out = f2h; K = 4096; ldN = 1024; k0 = (xx & 127) * 32; n0 = (xx >> 7) * 64; }
  {
    const int r = t >> 3, c = (t & 7) * 8;
    const float* wp = W + (long)(k0 + r) * ldN + n0 + c;
    *(float4*)&tile[r][c]     = *(const float4*)wp;
    *(float4*)&tile[r][c + 4] = *(const float4*)(wp + 4);
  }
  __syncthreads();
  const int fr = t & 15, kg = (t >> 4) & 3, nb = t >> 6;
  const int n = nb * 16 + fr;
  unsigned ph[4];
#pragma unroll
  for (int i = 0; i < 4; ++i) {
    const float x0 = tile[kg * 8 + 2 * i][n];
    const float x1 = tile[kg * 8 + 2 * i + 1][n];
    ph[i] = (unsigned)f2bf(x0) | ((unsigned)f2bf(x1) << 16);
  }
  const int tk = K >> 5;
  const long off = ((long)(n0 / 16 + nb) * tk + (k0 >> 5)) * 512 + kg * 128 + fr * 8;
  *(uint4*)(out + off) = make_uint4(ph[0], ph[1], ph[2], ph[3]);
}

// ---- attention weight convert (z=0..2 QKV->aWh hi, z=3 O->oWh hi) + fused bias copy ----
__global__ __launch_bounds__(256) void wconv_attn_kernel(
    const float* __restrict__ Wq, const float* __restrict__ Wk,
    const float* __restrict__ Wv, const float* __restrict__ Wo,
    const float* __restrict__ Bq, const float* __restrict__ Bk,
    const float* __restrict__ Bv,
    u16* __restrict__ aWh, u16* __restrict__ oWh, float* __restrict__ fusedB)
{
  __shared__ float tile[32][68];
  const int zz = blockIdx.z;
  const float* W = (zz == 0) ? Wq : (zz == 1) ? Wk : (zz == 2) ? Wv : Wo;
  u16* Wh = (zz < 3) ? aWh : oWh;
  const int obase = (zz < 3) ? zz * 1024 : 0;
  const int t = threadIdx.x;
  const int k0 = blockIdx.x * 32, n0 = blockIdx.y * 64;
  if (zz < 3 && blockIdx.x == 0 && blockIdx.y < 4) {
    const float* B = (zz == 0) ? Bq : (zz == 1) ? Bk : Bv;
    fusedB[zz * 1024 + blockIdx.y * 256 + t] = B[blockIdx.y * 256 + t];
  }
  {
    const int r = t >> 3, c = (t & 7) * 8;
    const float* wp = W + (long)(k0 + r) * 1024 + n0 + c;
    *(float4*)&tile[r][c]     = *(const float4*)wp;
    *(float4*)&tile[r][c + 4] = *(const float4*)(wp + 4);
  }
  __syncthreads();
  const int fr = t & 15, kg = (t >> 4) & 3, nb = t >> 6;
  const int n = nb * 16 + fr;
  unsigned ph[4];
#pragma unroll
  for (int i = 0; i < 4; ++i) {
    const float x0 = tile[kg * 8 + 2 * i][n];
    const float x1 = tile[kg * 8 + 2 * i + 1][n];
    ph[i] = (unsigned)f2bf(x0) | ((unsigned)f2bf(x1) << 16);
  }
  const long off = ((long)((obase + n0) / 16 + nb) * 32 + (k0 >> 5)) * 512 + kg * 128 + fr * 8;
  *(uint4*)(Wh + off) = make_uint4(ph[0], ph[1], ph[2], ph[3]);
}

// ---- tiled GEMM: C = A @ B^T (all bf16-hi). BK=64 (2 K-chunks per barrier). 4 waves (2x2).
// OUTMODE: 0 bias->C, 3 bias+relu->tiled hi, 4 exp(bias+acc)->C + row-sum partials,
//          5 fused QKV prep: rope Q/K (lane-pair shfl + tables) + V transpose -> qkvT tiles. ----
template<int BM, int BN, int OUTMODE>
__global__ __launch_bounds__(256) void gemm_t_kernel(
    const u16* __restrict__ Ah, const u16* __restrict__ Bh,
    const float* __restrict__ bias, float* __restrict__ C,
    u16* __restrict__ th, float* __restrict__ partial,
    u16* __restrict__ qkvT, const float* __restrict__ cosT,
    const float* __restrict__ sinT,
    int K, int tkA, int tkB, long ldc, int tkC, int colBase)
{
  constexpr int TA = BM / 16;
  constexpr int TB = BN / 16;
  constexpr int MREP = BM / 32;
  constexpr int NREP = BN / 32;
  constexpr int NTILES2 = (TA + TB) * 2;
  constexpr int NL2 = NTILES2 / 4;
  __shared__ __align__(16) u16 lds[NTILES2 * 512];
  const int tid = threadIdx.x, wid = tid >> 6, lane = tid & 63;
  const int fr = lane & 15, kg = lane >> 4;
  const int wr = wid >> 1, wc = wid & 1;
  const int row0 = blockIdx.x * BM, col0 = blockIdx.y * BN;
  const long aTile0 = (long)(row0 >> 4) * tkA;
  const long bTile0 = (long)(col0 >> 4) * tkB;
  const int laneOff = lane * 8;

  const u16* srcs[NL2];
  u16* dsts[NL2];
#pragma unroll
  for (int i = 0; i < NL2; ++i) {
    const int t2 = wid + i * 4;
    const int t = t2 >> 1, c = t2 & 1;
    const u16* s;
    if (t < TA) s = Ah + (aTile0 + (long)t * tkA) * 512;
    else        s = Bh + (bTile0 + (long)(t - TA) * tkB) * 512;
    srcs[i] = s + c * 512 + laneOff;
    dsts[i] = lds + t2 * 512;
  }

  f32x4 acc[MREP][NREP];
#pragma unroll
  for (int m = 0; m < MREP; ++m)
#pragma unroll
    for (int n = 0; n < NREP; ++n) acc[m][n] = {0.f, 0.f, 0.f, 0.f};

  const int fo = (kg * 16 + fr) * 8;
  const u16* sA_ = lds;
  const u16* sB_ = lds + TA * 2 * 512;

  for (int kc = 0; kc < (K >> 6); ++kc) {
#pragma unroll
    for (int i = 0; i < NL2; ++i) {
      load_lds16(srcs[i], dsts[i]);
      srcs[i] += 1024;
    }
    __syncthreads();
#pragma unroll
    for (int c = 0; c < 2; ++c) {
      bf16x8 fah[MREP], fbh[NREP];
#pragma unroll
      for (int m = 0; m < MREP; ++m)
        fah[m] = *(const bf16x8*)(sA_ + ((wr * MREP + m) * 2 + c) * 512 + fo);
#pragma unroll
      for (int n = 0; n < NREP; ++n)
        fbh[n] = *(const bf16x8*)(sB_ + ((wc * NREP + n) * 2 + c) * 512 + fo);
#pragma unroll
      for (int m = 0; m < MREP; ++m)
#pragma unroll
        for (int n = 0; n < NREP; ++n)
          acc[m][n] = __builtin_amdgcn_mfma_f32_16x16x32_bf16(fah[m], fbh[n], acc[m][n], 0, 0, 0);
    }
    __syncthreads();
  }
  if constexpr (OUTMODE == 3) {
#pragma unroll
    for (int n = 0; n < NREP; ++n) {
      const int col = col0 + (wc * NREP + n) * 16 + fr;
      const float bv = bias[col];
      const int k3 = (col >> 3) & 3;
      const int k7 = col & 7;
#pragma unroll
      for (int m = 0; m < MREP; ++m)
#pragma unroll
        for (int r = 0; r < 4; ++r) {
          const int row = row0 + (wr * MREP + m) * 16 + kg * 4 + r;
          const float v = fmaxf(acc[m][n][r] + bv, 0.f);
          const long off = ((long)(row >> 4) * tkC + (col >> 5)) * 512 + k3 * 128 + (row & 15) * 8 + k7;
          th[off] = f2bf(v);
        }
    }
  } else if constexpr (OUTMODE == 4) {
    __shared__ float rsum[BM];
    for (int i = tid; i < BM; i += 256) rsum[i] = 0.f;
    __syncthreads();
    float rs[MREP][4];
#pragma unroll
    for (int m = 0; m < MREP; ++m)
#pragma unroll
      for (int r = 0; r < 4; ++r) rs[m][r] = 0.f;
#pragma unroll
    for (int n = 0; n < NREP; ++n) {
      const int col = col0 + (wc * NREP + n) * 16 + fr;
      const float bv = bias[col];
#pragma unroll
      for (int m = 0; m < MREP; ++m)
#pragma unroll
        for (int r = 0; r < 4; ++r) {
          const long row = row0 + (wr * MREP + m) * 16 + kg * 4 + r;
          const float e = __expf(acc[m][n][r] + bv);
          C[row * ldc + col] = e;
          rs[m][r] += e;
        }
    }
#pragma unroll
    for (int m = 0; m < MREP; ++m)
#pragma unroll
      for (int r = 0; r < 4; ++r) {
#pragma unroll
        for (int off = 1; off < 16; off <<= 1) rs[m][r] += __shfl_xor(rs[m][r], off, 16);
        if (fr == 0) atomicAdd(&rsum[(wr * MREP + m) * 16 + kg * 4 + r], rs[m][r]);
      }
    __syncthreads();
    for (int i = tid; i < BM; i += 256)
      partial[(long)(row0 + i) * 256 + blockIdx.y] = rsum[i];
  } else if constexpr (OUTMODE == 5) {
    // fused QKV prep. Global col decides section: 0..1023 Q (rope*0.125), 1024..2047 K (rope),
    // 2048..3071 V (transpose-tiled). BN block lies entirely in one section (BN | 1024).
    const int gc0 = colBase + col0;
    const int sect = gc0 >> 10;
    u16* T = qkvT + (long)sect * 2097152;   // each tensor: 64 z * 32768
#pragma unroll
    for (int n = 0; n < NREP; ++n) {
      const int gcol = gc0 + (wc * NREP + n) * 16 + fr;
      const float bv = bias[gcol];
      const int hc = (gcol & 1023) >> 6;
      const int d = gcol & 63;
#pragma unroll
      for (int m = 0; m < MREP; ++m)
#pragma unroll
        for (int r = 0; r < 4; ++r) {
          const int row = row0 + (wr * MREP + m) * 16 + kg * 4 + r;
          const int b = row >> 9, s = row & 511;
          const float v = acc[m][n][r] + bv;
          const long zb = (long)(b * 16 + hc) * 32768;
          if (sect < 2) {
            const float vp = __shfl_xor(v, 1);
            const int i2 = d >> 1;
            const float cc = cosT[s * 32 + i2], ss = sinT[s * 32 + i2];
            float ro = (d & 1) ? (vp * ss + v * cc) : (v * cc - vp * ss);
            if (sect == 0) ro *= 0.125f;
            const long off = zb + ((long)(s >> 4) * 2 + (d >> 5)) * 512 +
                             ((d >> 3) & 3) * 128 + (s & 15) * 8 + (d & 7);
            T[off] = f2bf(ro);
          } else {
            const long off = zb + ((long)(d >> 4) * 16 + (s >> 5)) * 512 +
                             ((s >> 3) & 3) * 128 + (d & 15) * 8 + (s & 7);
            T[off] = f2bf(v);
          }
        }
    }
  } else {
#pragma unroll
    for (int n = 0; n < NREP; ++n) {
      const int col = col0 + (wc * NREP + n) * 16 + fr;
      const float bv = bias ? bias[col] : 0.f;
#pragma unroll
      for (int m = 0; m < MREP; ++m)
#pragma unroll
        for (int r = 0; r < 4; ++r) {
          const long row = row0 + (wr * MREP + m) * 16 + kg * 4 + r;
          C[row * ldc + col] = acc[m][n][r] + bv;
        }
    }
  }
}

// ---- flash attention: per block (64 q-rows, z=(b,h)); Q pre-scaled by 0.125.
// No online max (scores O(1)-bounded); masked -> -30 sentinel (uniform on all-masked rows). ----
__global__ __launch_bounds__(256) void flash_kernel(
    const u16* __restrict__ Qt, const u16* __restrict__ Kt,
    const u16* __restrict__ Vt, const int* __restrict__ tok,
    u16* __restrict__ Oh, int causal)
{
  __shared__ __align__(16) u16 sKV[16 * 512];   // K tiles 0..7, V tiles 8..15
  __shared__ __align__(16) u16 sP[8 * 512];     // P tiles / epilogue staging
  const int tid = threadIdx.x, wid = tid >> 6, lane = tid & 63;
  const int fr = lane & 15, kg = lane >> 4;
  const int qblk = blockIdx.x, z = blockIdx.y;  // qblk: 64 rows
  const int b = z >> 4, h = z & 15;
  const long zbase = (long)z * 32768;
  const int fo = (kg * 16 + fr) * 8;
  const int laneOff = lane * 8;
  int kblim = 8;
  if (causal && tok[b * 512] != 0) kblim = qblk + 1;
  bf16x8 qf[2];
#pragma unroll
  for (int kc = 0; kc < 2; ++kc)
    qf[kc] = *(const bf16x8*)(Qt + zbase + ((long)(qblk * 4 + wid) * 2 + kc) * 512 + fo);
  f32x4 acc_o[4];
  float lp[4];
#pragma unroll
  for (int n = 0; n < 4; ++n) acc_o[n] = {0.f, 0.f, 0.f, 0.f};
#pragma unroll
  for (int r = 0; r < 4; ++r) lp[r] = 0.f;

  for (int kb = 0; kb < kblim; ++kb) {
    __syncthreads();
#pragma unroll
    for (int i = 0; i < 4; ++i) {
      const int t = wid + i * 4;
      const u16* src;
      if (t < 8) src = Kt + zbase + (long)((kb * 4 + (t >> 1)) * 2 + (t & 1)) * 512;
      else       src = Vt + zbase + (long)(((t - 8) >> 1) * 16 + kb * 2 + (t & 1)) * 512;
      load_lds16(src + laneOff, sKV + t * 512);
    }
    __syncthreads();
    f32x4 s4[4];
#pragma unroll
    for (int n = 0; n < 4; ++n) s4[n] = {0.f, 0.f, 0.f, 0.f};
#pragma unroll
    for (int kc = 0; kc < 2; ++kc)
#pragma unroll
      for (int n = 0; n < 4; ++n) {
        const bf16x8 kf = *(const bf16x8*)(sKV + (n * 2 + kc) * 512 + fo);
        s4[n] = __builtin_amdgcn_mfma_f32_16x16x32_bf16(qf[kc], kf, s4[n], 0, 0, 0);
      }
    int tmask[4];
#pragma unroll
    for (int n = 0; n < 4; ++n) tmask[n] = tok[b * 512 + kb * 64 + n * 16 + fr];
#pragma unroll
    for (int r = 0; r < 4; ++r) {
      const int q = qblk * 64 + wid * 16 + kg * 4 + r;
#pragma unroll
      for (int n = 0; n < 4; ++n) {
        const int kcol = kb * 64 + n * 16 + fr;
        const bool ok = (tmask[n] != 0) && (!causal || kcol <= q);
        const float p = __expf(ok ? s4[n][r] : -30.0f);
        lp[r] += p;
        const int k3 = (n & 1) * 2 + (fr >> 3);
        sP[(wid * 2 + (n >> 1)) * 512 + k3 * 128 + (kg * 4 + r) * 8 + (fr & 7)] = f2bf(p);
      }
    }
    __syncthreads();
#pragma unroll
    for (int kc = 0; kc < 2; ++kc) {
      const bf16x8 pf = *(const bf16x8*)(sP + (wid * 2 + kc) * 512 + fo);
#pragma unroll
      for (int n = 0; n < 4; ++n) {
        const bf16x8 vf = *(const bf16x8*)(sKV + (8 + n * 2 + kc) * 512 + fo);
        acc_o[n] = __builtin_amdgcn_mfma_f32_16x16x32_bf16(pf, vf, acc_o[n], 0, 0, 0);
      }
    }
  }
#pragma unroll
  for (int r = 0; r < 4; ++r) {
    float s = lp[r];
#pragma unroll
    for (int off = 1; off < 16; off <<= 1) s += __shfl_xor(s, off, 16);
    const float inv = 1.0f / s;
#pragma unroll
    for (int n = 0; n < 4; ++n) acc_o[n][r] *= inv;
  }
  __syncthreads();
#pragma unroll
  for (int n = 0; n < 4; ++n)
#pragma unroll
    for (int r = 0; r < 4; ++r) {
      const int k3 = (n & 1) * 2 + (fr >> 3);
      sP[(wid * 2 + (n >> 1)) * 512 + k3 * 128 + (kg * 4 + r) * 8 + (fr & 7)] = f2bf(acc_o[n][r]);
    }
  __syncthreads();
  const long rbg = (long)b * 32 + qblk * 4 + wid;
#pragma unroll
  for (int i = 0; i < 2; ++i) {
    const long off = (rbg * 32 + h * 2 + i) * 512 + laneOff;
    *(uint4*)(Oh + off) = *(const uint4*)(sP + (wid * 2 + i) * 512 + laneOff);
  }
}

// ---- out = LayerNorm(X + R)*g + be ; writes fp32 + tiled hi ----
__global__ __launch_bounds__(256) void ln_fused_kernel(
    const float* __restrict__ X, const float* __restrict__ R,
    const float* __restrict__ g, const float* __restrict__ be,
    float* __restrict__ Out, u16* __restrict__ th)
{
  __shared__ float red[8];
  const int tid = threadIdx.x;
  const long row = blockIdx.x;
  const int k0 = tid * 4;
  const float4 xv = *(const float4*)(X + row * DMODEL + k0);
  const float4 rv = *(const float4*)(R + row * DMODEL + k0);
  const float v0 = xv.x + rv.x, v1 = xv.y + rv.y, v2 = xv.z + rv.z, v3 = xv.w + rv.w;
  float s = waveSum((v0 + v1) + (v2 + v3));
  const int wv = tid >> 6, ln = tid & 63;
  if (ln == 0) red[wv] = s;
  __syncthreads();
  const float mu = (red[0] + red[1] + red[2] + red[3]) * (1.0f / DMODEL);
  const float d0 = v0 - mu, d1 = v1 - mu, d2 = v2 - mu, d3 = v3 - mu;
  float sq = waveSum(d0 * d0 + d1 * d1 + d2 * d2 + d3 * d3);
  if (ln == 0) red[4 + wv] = sq;
  __syncthreads();
  const float var = (red[4] + red[5] + red[6] + red[7]) * (1.0f / DMODEL);
  const float rstd = 1.0f / sqrtf(var + 1e-5f);
  const float4 gv = *(const float4*)(g + k0);
  const float4 bv = *(const float4*)(be + k0);
  float4 o;
  o.x = d0 * rstd * gv.x + bv.x;
  o.y = d1 * rstd * gv.y + bv.y;
  o.z = d2 * rstd * gv.z + bv.z;
  o.w = d3 * rstd * gv.w + bv.w;
  *(float4*)(Out + row * DMODEL + k0) = o;
  const long off = ((row >> 4) * 32 + (k0 >> 5)) * 512 +
                   (long)(((k0 & 31) >> 3)) * 128 + (row & 15) * 8 + (k0 & 7);
  uint2 uh;
  uh.x = (unsigned)f2bf(o.x) | ((unsigned)f2bf(o.y) << 16);
  uh.y = (unsigned)f2bf(o.z) | ((unsigned)f2bf(o.w) << 16);
  *(uint2*)(th + off) = uh;
}

// ---- vocab normalize: P holds exp'd logits; partial[row][250] block sums ----
__global__ __launch_bounds__(256) void vocab_norm_kernel(
    float* __restrict__ P, const float* __restrict__ partial)
{
  __shared__ float red[4];
  const int tid = threadIdx.x;
  const long row = blockIdx.x;
  float s = (tid < 250) ? partial[row * 256 + tid] : 0.f;
  s = waveSum(s);
  const int wv = tid >> 6, ln = tid & 63;
  if (ln == 0) red[wv] = s;
  __syncthreads();
  const float inv = 1.0f / (red[0] + red[1] + red[2] + red[3]);
  float4* p = (float4*)(P + row * VOCAB);
  for (int i = tid; i < VOCAB / 4; i += 256) {
    float4 v = p[i];
    v.x *= inv; v.y *= inv; v.z *= inv; v.w *= inv;
    p[i] = v;
  }
}

extern "C" void kernel_launch(void* const* d_in, const int* in_sizes, int n_in,
                              void* d_out, int out_size, void* d_ws, size_t ws_size,
                              hipStream_t stream)
{
  (void)in_sizes; (void)n_in; (void)out_size; (void)ws_size;
  const int* src = (const int*)d_in[0];
  const int* tgt = (const int*)d_in[1];
  const float* enc_emb = (const float*)d_in[2];
  const float* dec_emb = (const float*)d_in[3];
  const float* eWq = (const float*)d_in[4];
  const float* eWk = (const float*)d_in[5];
  const float* eWv = (const float*)d_in[6];
  const float* eWo = (const float*)d_in[7];
  const float* eBq = (const float*)d_in[8];
  const float* eBk = (const float*)d_in[9];
  const float* eBv = (const float*)d_in[10];
  const float* eBo = (const float*)d_in[11];
  const float* eL1g = (const float*)d_in[12];
  const float* eL1b = (const float*)d_in[13];
  const float* eL2g = (const float*)d_in[14];
  const float* eL2b = (const float*)d_in[15];
  const float* eF1  = (const float*)d_in[16];
  const float* eF1b = (const float*)d_in[17];
  const float* eF2  = (const float*)d_in[18];
  const float* eF2b = (const float*)d_in[19];
  const float* dsWq = (const float*)d_in[20];
  const float* dsWk = (const float*)d_in[21];
  const float* dsWv = (const float*)d_in[22];
  const float* dsWo = (const float*)d_in[23];
  const float* dcWq = (const float*)d_in[24];
  const float* dcWk = (const float*)d_in[25];
  const float* dcWv = (const float*)d_in[26];
  const float* dcWo = (const float*)d_in[27];
  const float* dsBq = (const float*)d_in[28];
  const float* dsBk = (const float*)d_in[29];
  const float* dsBv = (const float*)d_in[30];
  const float* dsBo = (const float*)d_in[31];
  const float* dcBq = (const float*)d_in[32];
  const float* dcBk = (const float*)d_in[33];
  const float* dcBv = (const float*)d_in[34];
  const float* dcBo = (const float*)d_in[35];
  const float* dL1g = (const float*)d_in[36];
  const float* dL2g = (const float*)d_in[37];
  const float* dL3g = (const float*)d_in[38];
  const float* dL1b = (const float*)d_in[39];
  const float* dL2b = (const float*)d_in[40];
  const float* dL3b = (const float*)d_in[41];
  const float* dF1  = (const float*)d_in[42];
  const float* dF1b = (const float*)d_in[43];
  const float* dF2  = (const float*)d_in[44];
  const float* dF2b = (const float*)d_in[45];
  const float* fW   = (const float*)d_in[46];
  const float* fb   = (const float*)d_in[47];

  // ---- workspace carve (~102 MiB) ----
  char* base = (char*)d_ws;
  auto alloc = [&](size_t bytes) { char* p = base; base += (bytes + 1023) & ~(size_t)1023; return p; };
  float* cosT   = (float*)alloc(SEQLEN * 32 * 4);
  float* sinT   = (float*)alloc(SEQLEN * 32 * 4);
  float* fusedB = (float*)alloc(3072 * 4);
  float* xb  = (float*)alloc((long)MROWS * DMODEL * 4);
  float* yb  = (float*)alloc((long)MROWS * DMODEL * 4);
  float* pb  = (float*)alloc((long)MROWS * DMODEL * 4);
  u16*   mt  = (u16*)alloc((long)MROWS * DMODEL * 2);   // encoder memory, tiled hi
  char* rA = base;
  u16* sth  = (u16*)(rA + 0 * MiB);     // stream tiled hi (4 MiB)
  // attention set
  u16* aWh  = (u16*)(rA + 8 * MiB);     // 6 MiB (3072x1024 hi)
  u16* qkvT = (u16*)(rA + 14 * MiB);    // 12 MiB: Qt +0, Kt +2M elems, Vt +4M elems
  u16* ath  = (u16*)(rA + 26 * MiB);    // 4 MiB
  u16* oWh  = (u16*)(rA + 30 * MiB);    // 2 MiB (ends 32)
  // FFN set (attention buffers dead)
  u16* f1h = (u16*)(rA + 8 * MiB);      // 8 MiB (4096x1024)
  u16* f2h = (u16*)(rA + 16 * MiB);     // 8 MiB (1024x4096)
  u16* fth = (u16*)(rA + 24 * MiB);     // 16 MiB (2048x4096 hi)
  // vocab set
  u16* vh  = (u16*)(rA + 8 * MiB);      // 62.5 MiB (32000x1024), ends 70.5
  float* vpart = (float*)(rA + 71 * MiB); // 2 MiB (2048x256 row partials)
  u16* Qt = qkvT;
  u16* Kt = qkvT + 2097152;
  u16* Vt = qkvT + 2 * 2097152;

  const long DD = (long)DMODEL * DMODEL;
  const long DF = (long)DMODEL * DFFN;

  rope_tab_kernel<<<(SEQLEN * 32) / 256, 256, 0, stream>>>(cosT, sinT);

  auto attention = [&](int self, const float* Wq, const float* Bq,
                       const float* Wk, const float* Bk,
                       const float* Wv, const float* Bv,
                       const float* Wo, const float* Bo,
                       const int* tok, int causal) {
    wconv_attn_kernel<<<dim3(32, 16, 4), 256, 0, stream>>>(
        Wq, Wk, Wv, Wo, Bq, Bk, Bv, aWh, oWh, fusedB);
    if (self) {
      gemm_t_kernel<128, 128, 5><<<dim3(16, 24), 256, 0, stream>>>(
          sth, aWh, fusedB, nullptr, nullptr, nullptr, qkvT, cosT, sinT,
          1024, 32, 32, 0, 0, 0);
    } else {
      gemm_t_kernel<64, 64, 5><<<dim3(32, 16), 256, 0, stream>>>(
          sth, aWh, fusedB, nullptr, nullptr, nullptr, qkvT, cosT, sinT,
          1024, 32, 32, 0, 0, 0);
      gemm_t_kernel<128, 128, 5><<<dim3(16, 16), 256, 0, stream>>>(
          mt, aWh + (long)64 * 32 * 512, fusedB, nullptr, nullptr, nullptr, qkvT, cosT, sinT,
          1024, 32, 32, 0, 0, 1024);
    }
    flash_kernel<<<dim3(8, 64), 256, 0, stream>>>(Qt, Kt, Vt, tok, ath, causal);
    gemm_t_kernel<64, 64, 0><<<dim3(32, 16), 256, 0, stream>>>(
        ath, oWh, Bo, pb, nullptr, nullptr, nullptr, nullptr, nullptr,
        1024, 32, 32, 1024, 0, 0);
  };

  auto ffn = [&](const float* W1, const float* B1, const float* W2, const float* B2) {
    wconv_ffn_kernel<<<4096, 256, 0, stream>>>(W1, W2, f1h, f2h);
    gemm_t_kernel<128, 128, 3><<<dim3(16, 32), 256, 0, stream>>>(
        sth, f1h, B1, nullptr, fth, nullptr, nullptr, nullptr, nullptr,
        1024, 32, 32, 0, 128, 0);
    gemm_t_kernel<64, 64, 0><<<dim3(32, 16), 256, 0, stream>>>(
        fth, f2h, B2, pb, nullptr, nullptr, nullptr, nullptr, nullptr,
        4096, 128, 128, 1024, 0, 0);
  };

  // -------- encoder --------
  embed_t_kernel<<<MROWS, 256, 0, stream>>>(src, enc_emb, xb, sth);
  for (int l = 0; l < NLAYER; ++l) {
    attention(1, eWq + l * DD, eBq + l * DMODEL, eWk + l * DD, eBk + l * DMODEL,
              eWv + l * DD, eBv + l * DMODEL, eWo + l * DD, eBo + l * DMODEL, src, 0);
    ln_fused_kernel<<<MROWS, 256, 0, stream>>>(xb, pb, eL1g + l * DMODEL, eL1b + l * DMODEL,
                                               xb, sth);
    ffn(eF1 + l * DF, eF1b + l * DFFN, eF2 + l * DF, eF2b + l * DMODEL);
    ln_fused_kernel<<<MROWS, 256, 0, stream>>>(xb, pb, eL2g + l * DMODEL, eL2b + l * DMODEL,
                                               xb, (l == NLAYER - 1) ? mt : sth);
  }
  // -------- decoder --------
  embed_t_kernel<<<MROWS, 256, 0, stream>>>(tgt, dec_emb, yb, sth);
  for (int l = 0; l < NLAYER; ++l) {
    attention(1, dsWq + l * DD, dsBq + l * DMODEL, dsWk + l * DD, dsBk + l * DMODEL,
              dsWv + l * DD, dsBv + l * DMODEL, dsWo + l * DD, dsBo + l * DMODEL, tgt, 1);
    ln_fused_kernel<<<MROWS, 256, 0, stream>>>(yb, pb, dL1g + l * DMODEL, dL1b + l * DMODEL,
                                               yb, sth);
    attention(0, dcWq + l * DD, dcBq + l * DMODEL, dcWk + l * DD, dcBk + l * DMODEL,
              dcWv + l * DD, dcBv + l * DMODEL, dcWo + l * DD, dcBo + l * DMODEL, src, 0);
    ln_fused_kernel<<<MROWS, 256, 0, stream>>>(yb, pb, dL2g + l * DMODEL, dL2b + l * DMODEL,
                                               yb, sth);
    ffn(dF1 + l * DF, dF1b + l * DFFN, dF2 + l * DF, dF2b + l * DMODEL);
    ln_fused_kernel<<<MROWS, 256, 0, stream>>>(yb, pb, dL3g + l * DMODEL, dL3b + l * DMODEL,
                                               yb, sth);
  }
  // -------- final projection (exp fused) + normalize --------
  float* outp = (float*)d_out;
  wconv_kernel<<<dim3(32, 500), 256, 0, stream>>>(fW, vh, 1024, VOCAB, 0);
  gemm_t_kernel<256, 128, 4><<<dim3(8, 250), 256, 0, stream>>>(
      sth, vh, fb, outp, nullptr, vpart, nullptr, nullptr, nullptr,
      1024, 32, 32, VOCAB, 0, 0);
  vocab_norm_kernel<<<MROWS, 256, 0, stream>>>(outp, vpart);
}

// Round 10
// 2871.144 us; speedup vs baseline: 1.0460x; 1.0460x over previous
//
#include <hip/hip_runtime.h>
#include <math.h>

#define NLAYER 6
#define DMODEL 1024
#define NHEAD  16
#define DFFN   4096
#define VOCAB  32000
#define NBATCH 4
#define SEQLEN 512
#define HDIM   64
#define MROWS  (NBATCH*SEQLEN)
#define MiB    (1024L*1024L)

typedef __attribute__((ext_vector_type(8))) short bf16x8;
typedef __attribute__((ext_vector_type(4))) float f32x4;
typedef unsigned short u16;

__device__ __forceinline__ float waveSum(float v) {
#pragma unroll
  for (int off = 32; off > 0; off >>= 1) v += __shfl_xor(v, off);
  return v;
}
__device__ __forceinline__ u16 f2bf(float x) {
  unsigned u = __float_as_uint(x);
  u += 0x7FFFu + ((u >> 16) & 1u);   // RNE
  return (u16)(u >> 16);
}
__device__ __forceinline__ float bf2f(u16 h) {
  return __uint_as_float((unsigned)h << 16);
}
__device__ __forceinline__ void load_lds16(const u16* src, u16* dst) {
  __builtin_amdgcn_global_load_lds(
      (const __attribute__((address_space(1))) unsigned int*)src,
      (__attribute__((address_space(3))) unsigned int*)dst, 16, 0, 0);
}

// Tiled bf16 layout: tile(rb,kc) of a [R][K] matrix = 16 rows x 32 K (1 KiB).
// base = (rb*(K/32)+kc)*512 ; elem(row,k) = ((k>>3)&3)*128 + (row&15)*8 + (k&7)

// ---- embedding gather + fp32 out + tiled hi ----
__global__ __launch_bounds__(256) void embed_t_kernel(
    const int* __restrict__ tok, const float* __restrict__ emb,
    float* __restrict__ out, u16* __restrict__ th)
{
  const long row = blockIdx.x;
  const int t = tok[row];
  const int k0 = threadIdx.x * 4;
  const float4 v = *(const float4*)(emb + (long)t * DMODEL + k0);
  *(float4*)(out + row * DMODEL + k0) = v;
  const long off = ((row >> 4) * 32 + (k0 >> 5)) * 512 +
                   (long)(((k0 & 31) >> 3)) * 128 + (row & 15) * 8 + (k0 & 7);
  uint2 uh;
  uh.x = (unsigned)f2bf(v.x) | ((unsigned)f2bf(v.y) << 16);
  uh.y = (unsigned)f2bf(v.z) | ((unsigned)f2bf(v.w) << 16);
  *(uint2*)(th + off) = uh;
}

// ---- rope tables ----
__global__ __launch_bounds__(256) void rope_tab_kernel(float* __restrict__ cosT, float* __restrict__ sinT)
{
  const int idx = blockIdx.x * 256 + threadIdx.x;   // < SEQLEN*32
  const int s = idx >> 5, i = idx & 31;
  const float e = (float)(2 * i) / 64.0f;
  const float inv = 1.0f / powf(10000.0f, e);
  const float ang = (float)s * inv;
  cosT[idx] = cosf(ang);
  sinT[idx] = sinf(ang);
}

// ---- generic weight convert: W[K][ldN] fp32 slice -> tiled bf16 hi ----
__global__ __launch_bounds__(256) void wconv_kernel(
    const float* __restrict__ W, u16* __restrict__ Wh,
    int K, int ldN, int nbase)
{
  __shared__ float tile[32][68];
  const int t = threadIdx.x;
  const int k0 = blockIdx.x * 32, n0 = blockIdx.y * 64;
  {
    const int r = t >> 3, c = (t & 7) * 8;
    const float* wp = W + (long)(k0 + r) * ldN + nbase + n0 + c;
    *(float4*)&tile[r][c]     = *(const float4*)wp;
    *(float4*)&tile[r][c + 4] = *(const float4*)(wp + 4);
  }
  __syncthreads();
  const int fr = t & 15, kg = (t >> 4) & 3, nb = t >> 6;
  const int n = nb * 16 + fr;
  unsigned ph[4];
#pragma unroll
  for (int i = 0; i < 4; ++i) {
    const float x0 = tile[kg * 8 + 2 * i][n];
    const float x1 = tile[kg * 8 + 2 * i + 1][n];
    ph[i] = (unsigned)f2bf(x0) | ((unsigned)f2bf(x1) << 16);
  }
  const int tk = K >> 5;
  const long off = ((long)(n0 / 16 + nb) * tk + (k0 >> 5)) * 512 + kg * 128 + fr * 8;
  *(uint4*)(Wh + off) = make_uint4(ph[0], ph[1], ph[2], ph[3]);
}

// ---- FFN weight convert: W1 and W2 -> tiled hi, single launch ----
__global__ __launch_bounds__(256) void wconv_ffn_kernel(
    const float* __restrict__ W1, const float* __restrict__ W2,
    u16* __restrict__ f1h, u16* __restrict__ f2h)
{
  __shared__ float tile[32][68];
  const int bx = blockIdx.x, t = threadIdx.x;
  const float* W; u16* out; int K, ldN, k0, n0;
  if (bx < 2048) { W = W1; out = f1h; K = 1024; ldN = 4096; k0 = (bx & 31) * 32;  n0 = (bx >> 5) * 64; }
  else { const int xx = bx - 2048; W = W2; out = f2h; K = 4096; ldN = 1024; k0 = (xx & 127) * 32; n0 = (xx >> 7) * 64; }
  {
    const int r = t >> 3, c = (t & 7) * 8;
    const float* wp = W + (long)(k0 + r) * ldN + n0 + c;
    *(float4*)&tile[r][c]     = *(const float4*)wp;
    *(float4*)&tile[r][c + 4] = *(const float4*)(wp + 4);
  }
  __syncthreads();
  const int fr = t & 15, kg = (t >> 4) & 3, nb = t >> 6;
  const int n = nb * 16 + fr;
  unsigned ph[4];
#pragma unroll
  for (int i = 0; i < 4; ++i) {
    const float x0 = tile[kg * 8 + 2 * i][n];
    const float x1 = tile[kg * 8 + 2 * i + 1][n];
    ph[i] = (unsigned)f2bf(x0) | ((unsigned)f2bf(x1) << 16);
  }
  const int tk = K >> 5;
  const long off = ((long)(n0 / 16 + nb) * tk + (k0 >> 5)) * 512 + kg * 128 + fr * 8;
  *(uint4*)(out + off) = make_uint4(ph[0], ph[1], ph[2], ph[3]);
}

// ---- attention weight convert (z=0..2 QKV->aWh hi, z=3 O->oWh hi) + fused bias copy ----
__global__ __launch_bounds__(256) void wconv_attn_kernel(
    const float* __restrict__ Wq, const float* __restrict__ Wk,
    const float* __restrict__ Wv, const float* __restrict__ Wo,
    const float* __restrict__ Bq, const float* __restrict__ Bk,
    const float* __restrict__ Bv,
    u16* __restrict__ aWh, u16* __restrict__ oWh, float* __restrict__ fusedB)
{
  __shared__ float tile[32][68];
  const int zz = blockIdx.z;
  const float* W = (zz == 0) ? Wq : (zz == 1) ? Wk : (zz == 2) ? Wv : Wo;
  u16* Wh = (zz < 3) ? aWh : oWh;
  const int obase = (zz < 3) ? zz * 1024 : 0;
  const int t = threadIdx.x;
  const int k0 = blockIdx.x * 32, n0 = blockIdx.y * 64;
  if (zz < 3 && blockIdx.x == 0 && blockIdx.y < 4) {
    const float* B = (zz == 0) ? Bq : (zz == 1) ? Bk : Bv;
    fusedB[zz * 1024 + blockIdx.y * 256 + t] = B[blockIdx.y * 256 + t];
  }
  {
    const int r = t >> 3, c = (t & 7) * 8;
    const float* wp = W + (long)(k0 + r) * 1024 + n0 + c;
    *(float4*)&tile[r][c]     = *(const float4*)wp;
    *(float4*)&tile[r][c + 4] = *(const float4*)(wp + 4);
  }
  __syncthreads();
  const int fr = t & 15, kg = (t >> 4) & 3, nb = t >> 6;
  const int n = nb * 16 + fr;
  unsigned ph[4];
#pragma unroll
  for (int i = 0; i < 4; ++i) {
    const float x0 = tile[kg * 8 + 2 * i][n];
    const float x1 = tile[kg * 8 + 2 * i + 1][n];
    ph[i] = (unsigned)f2bf(x0) | ((unsigned)f2bf(x1) << 16);
  }
  const long off = ((long)((obase + n0) / 16 + nb) * 32 + (k0 >> 5)) * 512 + kg * 128 + fr * 8;
  *(uint4*)(Wh + off) = make_uint4(ph[0], ph[1], ph[2], ph[3]);
}

// ---- tiled GEMM: C = A @ B^T (all bf16-hi). CH = 32-K chunks per barrier (1 or 2).
// 4 waves (2x2). OUTMODE: 0 bias->C, 3 bias+relu->tiled hi, 4 exp(bias+acc)->C + row partials,
//          5 fused QKV prep: rope Q/K (lane-pair shfl + tables) + V transpose -> qkvT tiles. ----
template<int BM, int BN, int OUTMODE, int CH>
__global__ __launch_bounds__(256) void gemm_t_kernel(
    const u16* __restrict__ Ah, const u16* __restrict__ Bh,
    const float* __restrict__ bias, float* __restrict__ C,
    u16* __restrict__ th, float* __restrict__ partial,
    u16* __restrict__ qkvT, const float* __restrict__ cosT,
    const float* __restrict__ sinT,
    int K, int tkA, int tkB, long ldc, int tkC, int colBase)
{
  constexpr int TA = BM / 16;
  constexpr int TB = BN / 16;
  constexpr int MREP = BM / 32;
  constexpr int NREP = BN / 32;
  constexpr int NTILES2 = (TA + TB) * CH;
  constexpr int NL2 = NTILES2 / 4;
  __shared__ __align__(16) u16 lds[NTILES2 * 512];
  const int tid = threadIdx.x, wid = tid >> 6, lane = tid & 63;
  const int fr = lane & 15, kg = lane >> 4;
  const int wr = wid >> 1, wc = wid & 1;
  const int row0 = blockIdx.x * BM, col0 = blockIdx.y * BN;
  const long aTile0 = (long)(row0 >> 4) * tkA;
  const long bTile0 = (long)(col0 >> 4) * tkB;
  const int laneOff = lane * 8;

  const u16* srcs[NL2];
  u16* dsts[NL2];
#pragma unroll
  for (int i = 0; i < NL2; ++i) {
    const int t2 = wid + i * 4;
    const int t = t2 / CH, c = t2 % CH;
    const u16* s;
    if (t < TA) s = Ah + (aTile0 + (long)t * tkA) * 512;
    else        s = Bh + (bTile0 + (long)(t - TA) * tkB) * 512;
    srcs[i] = s + c * 512 + laneOff;
    dsts[i] = lds + t2 * 512;
  }

  f32x4 acc[MREP][NREP];
#pragma unroll
  for (int m = 0; m < MREP; ++m)
#pragma unroll
    for (int n = 0; n < NREP; ++n) acc[m][n] = {0.f, 0.f, 0.f, 0.f};

  const int fo = (kg * 16 + fr) * 8;
  const u16* sA_ = lds;
  const u16* sB_ = lds + TA * CH * 512;

  for (int kc = 0; kc < K / (32 * CH); ++kc) {
#pragma unroll
    for (int i = 0; i < NL2; ++i) {
      load_lds16(srcs[i], dsts[i]);
      srcs[i] += CH * 512;
    }
    __syncthreads();
#pragma unroll
    for (int c = 0; c < CH; ++c) {
      bf16x8 fah[MREP], fbh[NREP];
#pragma unroll
      for (int m = 0; m < MREP; ++m)
        fah[m] = *(const bf16x8*)(sA_ + ((wr * MREP + m) * CH + c) * 512 + fo);
#pragma unroll
      for (int n = 0; n < NREP; ++n)
        fbh[n] = *(const bf16x8*)(sB_ + ((wc * NREP + n) * CH + c) * 512 + fo);
#pragma unroll
      for (int m = 0; m < MREP; ++m)
#pragma unroll
        for (int n = 0; n < NREP; ++n)
          acc[m][n] = __builtin_amdgcn_mfma_f32_16x16x32_bf16(fah[m], fbh[n], acc[m][n], 0, 0, 0);
    }
    __syncthreads();
  }
  if constexpr (OUTMODE == 3) {
#pragma unroll
    for (int n = 0; n < NREP; ++n) {
      const int col = col0 + (wc * NREP + n) * 16 + fr;
      const float bv = bias[col];
      const int k3 = (col >> 3) & 3;
      const int k7 = col & 7;
#pragma unroll
      for (int m = 0; m < MREP; ++m)
#pragma unroll
        for (int r = 0; r < 4; ++r) {
          const int row = row0 + (wr * MREP + m) * 16 + kg * 4 + r;
          const float v = fmaxf(acc[m][n][r] + bv, 0.f);
          const long off = ((long)(row >> 4) * tkC + (col >> 5)) * 512 + k3 * 128 + (row & 15) * 8 + k7;
          th[off] = f2bf(v);
        }
    }
  } else if constexpr (OUTMODE == 4) {
    __shared__ float rsum[BM];
    for (int i = tid; i < BM; i += 256) rsum[i] = 0.f;
    __syncthreads();
    float rs[MREP][4];
#pragma unroll
    for (int m = 0; m < MREP; ++m)
#pragma unroll
      for (int r = 0; r < 4; ++r) rs[m][r] = 0.f;
#pragma unroll
    for (int n = 0; n < NREP; ++n) {
      const int col = col0 + (wc * NREP + n) * 16 + fr;
      const float bv = bias[col];
#pragma unroll
      for (int m = 0; m < MREP; ++m)
#pragma unroll
        for (int r = 0; r < 4; ++r) {
          const long row = row0 + (wr * MREP + m) * 16 + kg * 4 + r;
          const float e = __expf(acc[m][n][r] + bv);
          C[row * ldc + col] = e;
          rs[m][r] += e;
        }
    }
#pragma unroll
    for (int m = 0; m < MREP; ++m)
#pragma unroll
      for (int r = 0; r < 4; ++r) {
#pragma unroll
        for (int off = 1; off < 16; off <<= 1) rs[m][r] += __shfl_xor(rs[m][r], off, 16);
        if (fr == 0) atomicAdd(&rsum[(wr * MREP + m) * 16 + kg * 4 + r], rs[m][r]);
      }
    __syncthreads();
    for (int i = tid; i < BM; i += 256)
      partial[(long)(row0 + i) * 256 + blockIdx.y] = rsum[i];
  } else if constexpr (OUTMODE == 5) {
    // fused QKV prep. Global col decides section: 0..1023 Q (rope*0.125), 1024..2047 K (rope),
    // 2048..3071 V (transpose-tiled). BN block lies entirely in one section.
    const int gc0 = colBase + col0;
    const int sect = gc0 >> 10;
    u16* T = qkvT + (long)sect * 2097152;   // each tensor: 64 z * 32768
#pragma unroll
    for (int n = 0; n < NREP; ++n) {
      const int gcol = gc0 + (wc * NREP + n) * 16 + fr;
      const float bv = bias[gcol];
      const int hc = (gcol & 1023) >> 6;
      const int d = gcol & 63;
#pragma unroll
      for (int m = 0; m < MREP; ++m)
#pragma unroll
        for (int r = 0; r < 4; ++r) {
          const int row = row0 + (wr * MREP + m) * 16 + kg * 4 + r;
          const int b = row >> 9, s = row & 511;
          const float v = acc[m][n][r] + bv;
          const long zb = (long)(b * 16 + hc) * 32768;
          if (sect < 2) {
            const float vp = __shfl_xor(v, 1);
            const int i2 = d >> 1;
            const float cc = cosT[s * 32 + i2], ss = sinT[s * 32 + i2];
            float ro = (d & 1) ? (vp * ss + v * cc) : (v * cc - vp * ss);
            if (sect == 0) ro *= 0.125f;
            const long off = zb + ((long)(s >> 4) * 2 + (d >> 5)) * 512 +
                             ((d >> 3) & 3) * 128 + (s & 15) * 8 + (d & 7);
            T[off] = f2bf(ro);
          } else {
            const long off = zb + ((long)(d >> 4) * 16 + (s >> 5)) * 512 +
                             ((s >> 3) & 3) * 128 + (d & 15) * 8 + (s & 7);
            T[off] = f2bf(v);
          }
        }
    }
  } else {
#pragma unroll
    for (int n = 0; n < NREP; ++n) {
      const int col = col0 + (wc * NREP + n) * 16 + fr;
      const float bv = bias ? bias[col] : 0.f;
#pragma unroll
      for (int m = 0; m < MREP; ++m)
#pragma unroll
        for (int r = 0; r < 4; ++r) {
          const long row = row0 + (wr * MREP + m) * 16 + kg * 4 + r;
          C[row * ldc + col] = acc[m][n][r] + bv;
        }
    }
  }
}

// ---- flash attention: per block (64 q-rows, z=(b,h)); Q pre-scaled by 0.125.
// No online max (scores O(1)-bounded); masked -> -30 sentinel (uniform on all-masked rows). ----
__global__ __launch_bounds__(256) void flash_kernel(
    const u16* __restrict__ Qt, const u16* __restrict__ Kt,
    const u16* __restrict__ Vt, const int* __restrict__ tok,
    u16* __restrict__ Oh, int causal)
{
  __shared__ __align__(16) u16 sKV[16 * 512];   // K tiles 0..7, V tiles 8..15
  __shared__ __align__(16) u16 sP[8 * 512];     // P tiles / epilogue staging
  const int tid = threadIdx.x, wid = tid >> 6, lane = tid & 63;
  const int fr = lane & 15, kg = lane >> 4;
  const int qblk = blockIdx.x, z = blockIdx.y;  // qblk: 64 rows
  const int b = z >> 4, h = z & 15;
  const long zbase = (long)z * 32768;
  const int fo = (kg * 16 + fr) * 8;
  const int laneOff = lane * 8;
  int kblim = 8;
  if (causal && tok[b * 512] != 0) kblim = qblk + 1;
  bf16x8 qf[2];
#pragma unroll
  for (int kc = 0; kc < 2; ++kc)
    qf[kc] = *(const bf16x8*)(Qt + zbase + ((long)(qblk * 4 + wid) * 2 + kc) * 512 + fo);
  f32x4 acc_o[4];
  float lp[4];
#pragma unroll
  for (int n = 0; n < 4; ++n) acc_o[n] = {0.f, 0.f, 0.f, 0.f};
#pragma unroll
  for (int r = 0; r < 4; ++r) lp[r] = 0.f;

  for (int kb = 0; kb < kblim; ++kb) {
    __syncthreads();
#pragma unroll
    for (int i = 0; i < 4; ++i) {
      const int t = wid + i * 4;
      const u16* src;
      if (t < 8) src = Kt + zbase + (long)((kb * 4 + (t >> 1)) * 2 + (t & 1)) * 512;
      else       src = Vt + zbase + (long)(((t - 8) >> 1) * 16 + kb * 2 + (t & 1)) * 512;
      load_lds16(src + laneOff, sKV + t * 512);
    }
    __syncthreads();
    f32x4 s4[4];
#pragma unroll
    for (int n = 0; n < 4; ++n) s4[n] = {0.f, 0.f, 0.f, 0.f};
#pragma unroll
    for (int kc = 0; kc < 2; ++kc)
#pragma unroll
      for (int n = 0; n < 4; ++n) {
        const bf16x8 kf = *(const bf16x8*)(sKV + (n * 2 + kc) * 512 + fo);
        s4[n] = __builtin_amdgcn_mfma_f32_16x16x32_bf16(qf[kc], kf, s4[n], 0, 0, 0);
      }
    int tmask[4];
#pragma unroll
    for (int n = 0; n < 4; ++n) tmask[n] = tok[b * 512 + kb * 64 + n * 16 + fr];
#pragma unroll
    for (int r = 0; r < 4; ++r) {
      const int q = qblk * 64 + wid * 16 + kg * 4 + r;
#pragma unroll
      for (int n = 0; n < 4; ++n) {
        const int kcol = kb * 64 + n * 16 + fr;
        const bool ok = (tmask[n] != 0) && (!causal || kcol <= q);
        const float p = __expf(ok ? s4[n][r] : -30.0f);
        lp[r] += p;
        const int k3 = (n & 1) * 2 + (fr >> 3);
        sP[(wid * 2 + (n >> 1)) * 512 + k3 * 128 + (kg * 4 + r) * 8 + (fr & 7)] = f2bf(p);
      }
    }
    __syncthreads();
#pragma unroll
    for (int kc = 0; kc < 2; ++kc) {
      const bf16x8 pf = *(const bf16x8*)(sP + (wid * 2 + kc) * 512 + fo);
#pragma unroll
      for (int n = 0; n < 4; ++n) {
        const bf16x8 vf = *(const bf16x8*)(sKV + (8 + n * 2 + kc) * 512 + fo);
        acc_o[n] = __builtin_amdgcn_mfma_f32_16x16x32_bf16(pf, vf, acc_o[n], 0, 0, 0);
      }
    }
  }
#pragma unroll
  for (int r = 0; r < 4; ++r) {
    float s = lp[r];
#pragma unroll
    for (int off = 1; off < 16; off <<= 1) s += __shfl_xor(s, off, 16);
    const float inv = 1.0f / s;
#pragma unroll
    for (int n = 0; n < 4; ++n) acc_o[n][r] *= inv;
  }
  __syncthreads();
#pragma unroll
  for (int n = 0; n < 4; ++n)
#pragma unroll
    for (int r = 0; r < 4; ++r) {
      const int k3 = (n & 1) * 2 + (fr >> 3);
      sP[(wid * 2 + (n >> 1)) * 512 + k3 * 128 + (kg * 4 + r) * 8 + (fr & 7)] = f2bf(acc_o[n][r]);
    }
  __syncthreads();
  const long rbg = (long)b * 32 + qblk * 4 + wid;
#pragma unroll
  for (int i = 0; i < 2; ++i) {
    const long off = (rbg * 32 + h * 2 + i) * 512 + laneOff;
    *(uint4*)(Oh + off) = *(const uint4*)(sP + (wid * 2 + i) * 512 + laneOff);
  }
}

// ---- out = LayerNorm(X + R)*g + be ; writes fp32 + tiled hi ----
__global__ __launch_bounds__(256) void ln_fused_kernel(
    const float* __restrict__ X, const float* __restrict__ R,
    const float* __restrict__ g, const float* __restrict__ be,
    float* __restrict__ Out, u16* __restrict__ th)
{
  __shared__ float red[8];
  const int tid = threadIdx.x;
  const long row = blockIdx.x;
  const int k0 = tid * 4;
  const float4 xv = *(const float4*)(X + row * DMODEL + k0);
  const float4 rv = *(const float4*)(R + row * DMODEL + k0);
  const float v0 = xv.x + rv.x, v1 = xv.y + rv.y, v2 = xv.z + rv.z, v3 = xv.w + rv.w;
  float s = waveSum((v0 + v1) + (v2 + v3));
  const int wv = tid >> 6, ln = tid & 63;
  if (ln == 0) red[wv] = s;
  __syncthreads();
  const float mu = (red[0] + red[1] + red[2] + red[3]) * (1.0f / DMODEL);
  const float d0 = v0 - mu, d1 = v1 - mu, d2 = v2 - mu, d3 = v3 - mu;
  float sq = waveSum(d0 * d0 + d1 * d1 + d2 * d2 + d3 * d3);
  if (ln == 0) red[4 + wv] = sq;
  __syncthreads();
  const float var = (red[4] + red[5] + red[6] + red[7]) * (1.0f / DMODEL);
  const float rstd = 1.0f / sqrtf(var + 1e-5f);
  const float4 gv = *(const float4*)(g + k0);
  const float4 bv = *(const float4*)(be + k0);
  float4 o;
  o.x = d0 * rstd * gv.x + bv.x;
  o.y = d1 * rstd * gv.y + bv.y;
  o.z = d2 * rstd * gv.z + bv.z;
  o.w = d3 * rstd * gv.w + bv.w;
  *(float4*)(Out + row * DMODEL + k0) = o;
  const long off = ((row >> 4) * 32 + (k0 >> 5)) * 512 +
                   (long)(((k0 & 31) >> 3)) * 128 + (row & 15) * 8 + (k0 & 7);
  uint2 uh;
  uh.x = (unsigned)f2bf(o.x) | ((unsigned)f2bf(o.y) << 16);
  uh.y = (unsigned)f2bf(o.z) | ((unsigned)f2bf(o.w) << 16);
  *(uint2*)(th + off) = uh;
}

// ---- vocab normalize: P holds exp'd logits; partial[row][250] block sums ----
__global__ __launch_bounds__(256) void vocab_norm_kernel(
    float* __restrict__ P, const float* __restrict__ partial)
{
  __shared__ float red[4];
  const int tid = threadIdx.x;
  const long row = blockIdx.x;
  float s = (tid < 250) ? partial[row * 256 + tid] : 0.f;
  s = waveSum(s);
  const int wv = tid >> 6, ln = tid & 63;
  if (ln == 0) red[wv] = s;
  __syncthreads();
  const float inv = 1.0f / (red[0] + red[1] + red[2] + red[3]);
  float4* p = (float4*)(P + row * VOCAB);
  for (int i = tid; i < VOCAB / 4; i += 256) {
    float4 v = p[i];
    v.x *= inv; v.y *= inv; v.z *= inv; v.w *= inv;
    p[i] = v;
  }
}

extern "C" void kernel_launch(void* const* d_in, const int* in_sizes, int n_in,
                              void* d_out, int out_size, void* d_ws, size_t ws_size,
                              hipStream_t stream)
{
  (void)in_sizes; (void)n_in; (void)out_size; (void)ws_size;
  const int* src = (const int*)d_in[0];
  const int* tgt = (const int*)d_in[1];
  const float* enc_emb = (const float*)d_in[2];
  const float* dec_emb = (const float*)d_in[3];
  const float* eWq = (const float*)d_in[4];
  const float* eWk = (const float*)d_in[5];
  const float* eWv = (const float*)d_in[6];
  const float* eWo = (const float*)d_in[7];
  const float* eBq = (const float*)d_in[8];
  const float* eBk = (const float*)d_in[9];
  const float* eBv = (const float*)d_in[10];
  const float* eBo = (const float*)d_in[11];
  const float* eL1g = (const float*)d_in[12];
  const float* eL1b = (const float*)d_in[13];
  const float* eL2g = (const float*)d_in[14];
  const float* eL2b = (const float*)d_in[15];
  const float* eF1  = (const float*)d_in[16];
  const float* eF1b = (const float*)d_in[17];
  const float* eF2  = (const float*)d_in[18];
  const float* eF2b = (const float*)d_in[19];
  const float* dsWq = (const float*)d_in[20];
  const float* dsWk = (const float*)d_in[21];
  const float* dsWv = (const float*)d_in[22];
  const float* dsWo = (const float*)d_in[23];
  const float* dcWq = (const float*)d_in[24];
  const float* dcWk = (const float*)d_in[25];
  const float* dcWv = (const float*)d_in[26];
  const float* dcWo = (const float*)d_in[27];
  const float* dsBq = (const float*)d_in[28];
  const float* dsBk = (const float*)d_in[29];
  const float* dsBv = (const float*)d_in[30];
  const float* dsBo = (const float*)d_in[31];
  const float* dcBq = (const float*)d_in[32];
  const float* dcBk = (const float*)d_in[33];
  const float* dcBv = (const float*)d_in[34];
  const float* dcBo = (const float*)d_in[35];
  const float* dL1g = (const float*)d_in[36];
  const float* dL2g = (const float*)d_in[37];
  const float* dL3g = (const float*)d_in[38];
  const float* dL1b = (const float*)d_in[39];
  const float* dL2b = (const float*)d_in[40];
  const float* dL3b = (const float*)d_in[41];
  const float* dF1  = (const float*)d_in[42];
  const float* dF1b = (const float*)d_in[43];
  const float* dF2  = (const float*)d_in[44];
  const float* dF2b = (const float*)d_in[45];
  const float* fW   = (const float*)d_in[46];
  const float* fb   = (const float*)d_in[47];

  // ---- workspace carve (~102 MiB) ----
  char* base = (char*)d_ws;
  auto alloc = [&](size_t bytes) { char* p = base; base += (bytes + 1023) & ~(size_t)1023; return p; };
  float* cosT   = (float*)alloc(SEQLEN * 32 * 4);
  float* sinT   = (float*)alloc(SEQLEN * 32 * 4);
  float* fusedB = (float*)alloc(3072 * 4);
  float* xb  = (float*)alloc((long)MROWS * DMODEL * 4);
  float* yb  = (float*)alloc((long)MROWS * DMODEL * 4);
  float* pb  = (float*)alloc((long)MROWS * DMODEL * 4);
  u16*   mt  = (u16*)alloc((long)MROWS * DMODEL * 2);   // encoder memory, tiled hi
  char* rA = base;
  u16* sth  = (u16*)(rA + 0 * MiB);     // stream tiled hi (4 MiB)
  // attention set
  u16* aWh  = (u16*)(rA + 8 * MiB);     // 6 MiB (3072x1024 hi)
  u16* qkvT = (u16*)(rA + 14 * MiB);    // 12 MiB: Qt +0, Kt +2M elems, Vt +4M elems
  u16* ath  = (u16*)(rA + 26 * MiB);    // 4 MiB
  u16* oWh  = (u16*)(rA + 30 * MiB);    // 2 MiB (ends 32)
  // FFN set (attention buffers dead)
  u16* f1h = (u16*)(rA + 8 * MiB);      // 8 MiB (4096x1024)
  u16* f2h = (u16*)(rA + 16 * MiB);     // 8 MiB (1024x4096)
  u16* fth = (u16*)(rA + 24 * MiB);     // 16 MiB (2048x4096 hi)
  // vocab set
  u16* vh  = (u16*)(rA + 8 * MiB);      // 62.5 MiB (32000x1024), ends 70.5
  float* vpart = (float*)(rA + 71 * MiB); // 2 MiB (2048x256 row partials)
  u16* Qt = qkvT;
  u16* Kt = qkvT + 2097152;
  u16* Vt = qkvT + 2 * 2097152;

  const long DD = (long)DMODEL * DMODEL;
  const long DF = (long)DMODEL * DFFN;

  rope_tab_kernel<<<(SEQLEN * 32) / 256, 256, 0, stream>>>(cosT, sinT);

  auto attention = [&](int self, const float* Wq, const float* Bq,
                       const float* Wk, const float* Bk,
                       const float* Wv, const float* Bv,
                       const float* Wo, const float* Bo,
                       const int* tok, int causal) {
    wconv_attn_kernel<<<dim3(32, 16, 4), 256, 0, stream>>>(
        Wq, Wk, Wv, Wo, Bq, Bk, Bv, aWh, oWh, fusedB);
    if (self) {
      gemm_t_kernel<128, 64, 5, 2><<<dim3(16, 48), 256, 0, stream>>>(
          sth, aWh, fusedB, nullptr, nullptr, nullptr, qkvT, cosT, sinT,
          1024, 32, 32, 0, 0, 0);
    } else {
      gemm_t_kernel<64, 64, 5, 2><<<dim3(32, 16), 256, 0, stream>>>(
          sth, aWh, fusedB, nullptr, nullptr, nullptr, qkvT, cosT, sinT,
          1024, 32, 32, 0, 0, 0);
      gemm_t_kernel<128, 64, 5, 2><<<dim3(16, 32), 256, 0, stream>>>(
          mt, aWh + (long)64 * 32 * 512, fusedB, nullptr, nullptr, nullptr, qkvT, cosT, sinT,
          1024, 32, 32, 0, 0, 1024);
    }
    flash_kernel<<<dim3(8, 64), 256, 0, stream>>>(Qt, Kt, Vt, tok, ath, causal);
    gemm_t_kernel<64, 64, 0, 2><<<dim3(32, 16), 256, 0, stream>>>(
        ath, oWh, Bo, pb, nullptr, nullptr, nullptr, nullptr, nullptr,
        1024, 32, 32, 1024, 0, 0);
  };

  auto ffn = [&](const float* W1, const float* B1, const float* W2, const float* B2) {
    wconv_ffn_kernel<<<4096, 256, 0, stream>>>(W1, W2, f1h, f2h);
    gemm_t_kernel<128, 64, 3, 2><<<dim3(16, 64), 256, 0, stream>>>(
        sth, f1h, B1, nullptr, fth, nullptr, nullptr, nullptr, nullptr,
        1024, 32, 32, 0, 128, 0);
    gemm_t_kernel<64, 64, 0, 2><<<dim3(32, 16), 256, 0, stream>>>(
        fth, f2h, B2, pb, nullptr, nullptr, nullptr, nullptr, nullptr,
        4096, 128, 128, 1024, 0, 0);
  };

  // -------- encoder --------
  embed_t_kernel<<<MROWS, 256, 0, stream>>>(src, enc_emb, xb, sth);
  for (int l = 0; l < NLAYER; ++l) {
    attention(1, eWq + l * DD, eBq + l * DMODEL, eWk + l * DD, eBk + l * DMODEL,
              eWv + l * DD, eBv + l * DMODEL, eWo + l * DD, eBo + l * DMODEL, src, 0);
    ln_fused_kernel<<<MROWS, 256, 0, stream>>>(xb, pb, eL1g + l * DMODEL, eL1b + l * DMODEL,
                                               xb, sth);
    ffn(eF1 + l * DF, eF1b + l * DFFN, eF2 + l * DF, eF2b + l * DMODEL);
    ln_fused_kernel<<<MROWS, 256, 0, stream>>>(xb, pb, eL2g + l * DMODEL, eL2b + l * DMODEL,
                                               xb, (l == NLAYER - 1) ? mt : sth);
  }
  // -------- decoder --------
  embed_t_kernel<<<MROWS, 256, 0, stream>>>(tgt, dec_emb, yb, sth);
  for (int l = 0; l < NLAYER; ++l) {
    attention(1, dsWq + l * DD, dsBq + l * DMODEL, dsWk + l * DD, dsBk + l * DMODEL,
              dsWv + l * DD, dsBv + l * DMODEL, dsWo + l * DD, dsBo + l * DMODEL, tgt, 1);
    ln_fused_kernel<<<MROWS, 256, 0, stream>>>(yb, pb, dL1g + l * DMODEL, dL1b + l * DMODEL,
                                               yb, sth);
    attention(0, dcWq + l * DD, dcBq + l * DMODEL, dcWk + l * DD, dcBk + l * DMODEL,
              dcWv + l * DD, dcBv + l * DMODEL, dcWo + l * DD, dcBo + l * DMODEL, src, 0);
    ln_fused_kernel<<<MROWS, 256, 0, stream>>>(yb, pb, dL2g + l * DMODEL, dL2b + l * DMODEL,
                                               yb, sth);
    ffn(dF1 + l * DF, dF1b + l * DFFN, dF2 + l * DF, dF2b + l * DMODEL);
    ln_fused_kernel<<<MROWS, 256, 0, stream>>>(yb, pb, dL3g + l * DMODEL, dL3b + l * DMODEL,
                                               yb, sth);
  }
  // -------- final projection (exp fused) + normalize --------
  float* outp = (float*)d_out;
  wconv_kernel<<<dim3(32, 500), 256, 0, stream>>>(fW, vh, 1024, VOCAB, 0);
  gemm_t_kernel<128, 128, 4, 1><<<dim3(16, 250), 256, 0, stream>>>(
      sth, vh, fb, outp, nullptr, vpart, nullptr, nullptr, nullptr,
      1024, 32, 32, VOCAB, 0, 0);
  vocab_norm_kernel<<<MROWS, 256, 0, stream>>>(outp, vpart);
}

// Round 11
// 2716.383 us; speedup vs baseline: 1.1056x; 1.0570x over previous
//
#include <hip/hip_runtime.h>
#include <math.h>

#define NLAYER 6
#define DMODEL 1024
#define NHEAD  16
#define DFFN   4096
#define VOCAB  32000
#define NBATCH 4
#define SEQLEN 512
#define HDIM   64
#define MROWS  (NBATCH*SEQLEN)
#define MiB    (1024L*1024L)

typedef __attribute__((ext_vector_type(8))) short bf16x8;
typedef __attribute__((ext_vector_type(4))) float f32x4;
typedef unsigned short u16;

__device__ __forceinline__ float waveSum(float v) {
#pragma unroll
  for (int off = 32; off > 0; off >>= 1) v += __shfl_xor(v, off);
  return v;
}
__device__ __forceinline__ u16 f2bf(float x) {
  unsigned u = __float_as_uint(x);
  u += 0x7FFFu + ((u >> 16) & 1u);   // RNE
  return (u16)(u >> 16);
}
__device__ __forceinline__ float bf2f(u16 h) {
  return __uint_as_float((unsigned)h << 16);
}
__device__ __forceinline__ void load_lds16(const u16* src, u16* dst) {
  __builtin_amdgcn_global_load_lds(
      (const __attribute__((address_space(1))) unsigned int*)src,
      (__attribute__((address_space(3))) unsigned int*)dst, 16, 0, 0);
}

// Tiled bf16 layout: tile(rb,kc) of a [R][K] matrix = 16 rows x 32 K (1 KiB).
// base = (rb*(K/32)+kc)*512 ; elem(row,k) = ((k>>3)&3)*128 + (row&15)*8 + (k&7)

// ---- embedding gather + fp32 out + tiled hi ----
__global__ __launch_bounds__(256) void embed_t_kernel(
    const int* __restrict__ tok, const float* __restrict__ emb,
    float* __restrict__ out, u16* __restrict__ th)
{
  const long row = blockIdx.x;
  const int t = tok[row];
  const int k0 = threadIdx.x * 4;
  const float4 v = *(const float4*)(emb + (long)t * DMODEL + k0);
  *(float4*)(out + row * DMODEL + k0) = v;
  const long off = ((row >> 4) * 32 + (k0 >> 5)) * 512 +
                   (long)(((k0 & 31) >> 3)) * 128 + (row & 15) * 8 + (k0 & 7);
  uint2 uh;
  uh.x = (unsigned)f2bf(v.x) | ((unsigned)f2bf(v.y) << 16);
  uh.y = (unsigned)f2bf(v.z) | ((unsigned)f2bf(v.w) << 16);
  *(uint2*)(th + off) = uh;
}

// ---- rope tables ----
__global__ __launch_bounds__(256) void rope_tab_kernel(float* __restrict__ cosT, float* __restrict__ sinT)
{
  const int idx = blockIdx.x * 256 + threadIdx.x;   // < SEQLEN*32
  const int s = idx >> 5, i = idx & 31;
  const float e = (float)(2 * i) / 64.0f;
  const float inv = 1.0f / powf(10000.0f, e);
  const float ang = (float)s * inv;
  cosT[idx] = cosf(ang);
  sinT[idx] = sinf(ang);
}

// ---- generic weight convert: W[K][ldN] fp32 slice -> tiled bf16 hi ----
__global__ __launch_bounds__(256) void wconv_kernel(
    const float* __restrict__ W, u16* __restrict__ Wh,
    int K, int ldN, int nbase)
{
  __shared__ float tile[32][68];
  const int t = threadIdx.x;
  const int k0 = blockIdx.x * 32, n0 = blockIdx.y * 64;
  {
    const int r = t >> 3, c = (t & 7) * 8;
    const float* wp = W + (long)(k0 + r) * ldN + nbase + n0 + c;
    *(float4*)&tile[r][c]     = *(const float4*)wp;
    *(float4*)&tile[r][c + 4] = *(const float4*)(wp + 4);
  }
  __syncthreads();
  const int fr = t & 15, kg = (t >> 4) & 3, nb = t >> 6;
  const int n = nb * 16 + fr;
  unsigned ph[4];
#pragma unroll
  for (int i = 0; i < 4; ++i) {
    const float x0 = tile[kg * 8 + 2 * i][n];
    const float x1 = tile[kg * 8 + 2 * i + 1][n];
    ph[i] = (unsigned)f2bf(x0) | ((unsigned)f2bf(x1) << 16);
  }
  const int tk = K >> 5;
  const long off = ((long)(n0 / 16 + nb) * tk + (k0 >> 5)) * 512 + kg * 128 + fr * 8;
  *(uint4*)(Wh + off) = make_uint4(ph[0], ph[1], ph[2], ph[3]);
}

// ---- FFN weight convert: W1 and W2 -> tiled hi, single launch ----
__global__ __launch_bounds__(256) void wconv_ffn_kernel(
    const float* __restrict__ W1, const float* __restrict__ W2,
    u16* __restrict__ f1h, u16* __restrict__ f2h)
{
  __shared__ float tile[32][68];
  const int bx = blockIdx.x, t = threadIdx.x;
  const float* W; u16* out; int K, ldN, k0, n0;
  if (bx < 2048) { W = W1; out = f1h; K = 1024; ldN = 4096; k0 = (bx & 31) * 32;  n0 = (bx >> 5) * 64; }
  else { const int xx = bx - 2048; W = W2; out = f2h; K = 4096; ldN = 1024; k0 = (xx & 127) * 32; n0 = (xx >> 7) * 64; }
  {
    const int r = t >> 3, c = (t & 7) * 8;
    const float* wp = W + (long)(k0 + r) * ldN + n0 + c;
    *(float4*)&tile[r][c]     = *(const float4*)wp;
    *(float4*)&tile[r][c + 4] = *(const float4*)(wp + 4);
  }
  __syncthreads();
  const int fr = t & 15, kg = (t >> 4) & 3, nb = t >> 6;
  const int n = nb * 16 + fr;
  unsigned ph[4];
#pragma unroll
  for (int i = 0; i < 4; ++i) {
    const float x0 = tile[kg * 8 + 2 * i][n];
    const float x1 = tile[kg * 8 + 2 * i + 1][n];
    ph[i] = (unsigned)f2bf(x0) | ((unsigned)f2bf(x1) << 16);
  }
  const int tk = K >> 5;
  const long off = ((long)(n0 / 16 + nb) * tk + (k0 >> 5)) * 512 + kg * 128 + fr * 8;
  *(uint4*)(out + off) = make_uint4(ph[0], ph[1], ph[2], ph[3]);
}

// ---- attention weight convert (z=0..2 QKV->aWh hi, z=3 O->oWh hi) + fused bias copy ----
__global__ __launch_bounds__(256) void wconv_attn_kernel(
    const float* __restrict__ Wq, const float* __restrict__ Wk,
    const float* __restrict__ Wv, const float* __restrict__ Wo,
    const float* __restrict__ Bq, const float* __restrict__ Bk,
    const float* __restrict__ Bv,
    u16* __restrict__ aWh, u16* __restrict__ oWh, float* __restrict__ fusedB)
{
  __shared__ float tile[32][68];
  const int zz = blockIdx.z;
  const float* W = (zz == 0) ? Wq : (zz == 1) ? Wk : (zz == 2) ? Wv : Wo;
  u16* Wh = (zz < 3) ? aWh : oWh;
  const int obase = (zz < 3) ? zz * 1024 : 0;
  const int t = threadIdx.x;
  const int k0 = blockIdx.x * 32, n0 = blockIdx.y * 64;
  if (zz < 3 && blockIdx.x == 0 && blockIdx.y < 4) {
    const float* B = (zz == 0) ? Bq : (zz == 1) ? Bk : Bv;
    fusedB[zz * 1024 + blockIdx.y * 256 + t] = B[blockIdx.y * 256 + t];
  }
  {
    const int r = t >> 3, c = (t & 7) * 8;
    const float* wp = W + (long)(k0 + r) * 1024 + n0 + c;
    *(float4*)&tile[r][c]     = *(const float4*)wp;
    *(float4*)&tile[r][c + 4] = *(const float4*)(wp + 4);
  }
  __syncthreads();
  const int fr = t & 15, kg = (t >> 4) & 3, nb = t >> 6;
  const int n = nb * 16 + fr;
  unsigned ph[4];
#pragma unroll
  for (int i = 0; i < 4; ++i) {
    const float x0 = tile[kg * 8 + 2 * i][n];
    const float x1 = tile[kg * 8 + 2 * i + 1][n];
    ph[i] = (unsigned)f2bf(x0) | ((unsigned)f2bf(x1) << 16);
  }
  const long off = ((long)((obase + n0) / 16 + nb) * 32 + (k0 >> 5)) * 512 + kg * 128 + fr * 8;
  *(uint4*)(Wh + off) = make_uint4(ph[0], ph[1], ph[2], ph[3]);
}

// ---- tiled GEMM: C = A @ B^T (all bf16-hi). CH = 32-K chunks per barrier.
// 4 waves (2x2). OUTMODE: 0 bias->C, 3 bias+relu->tiled hi, 4 exp(bias+acc)->C + row partials,
//          5 fused QKV prep: rope Q/K (lane-pair shfl + tables) + V transpose -> qkvT tiles. ----
template<int BM, int BN, int OUTMODE, int CH>
__global__ __launch_bounds__(256) void gemm_t_kernel(
    const u16* __restrict__ Ah, const u16* __restrict__ Bh,
    const float* __restrict__ bias, float* __restrict__ C,
    u16* __restrict__ th, float* __restrict__ partial,
    u16* __restrict__ qkvT, const float* __restrict__ cosT,
    const float* __restrict__ sinT,
    int K, int tkA, int tkB, long ldc, int tkC, int colBase)
{
  constexpr int TA = BM / 16;
  constexpr int TB = BN / 16;
  constexpr int MREP = BM / 32;
  constexpr int NREP = BN / 32;
  constexpr int NTILES2 = (TA + TB) * CH;
  constexpr int NL2 = NTILES2 / 4;
  __shared__ __align__(16) u16 lds[NTILES2 * 512];
  const int tid = threadIdx.x, wid = tid >> 6, lane = tid & 63;
  const int fr = lane & 15, kg = lane >> 4;
  const int wr = wid >> 1, wc = wid & 1;
  const int row0 = blockIdx.x * BM, col0 = blockIdx.y * BN;
  const long aTile0 = (long)(row0 >> 4) * tkA;
  const long bTile0 = (long)(col0 >> 4) * tkB;
  const int laneOff = lane * 8;

  const u16* srcs[NL2];
  u16* dsts[NL2];
#pragma unroll
  for (int i = 0; i < NL2; ++i) {
    const int t2 = wid + i * 4;
    const int t = t2 / CH, c = t2 % CH;
    const u16* s;
    if (t < TA) s = Ah + (aTile0 + (long)t * tkA) * 512;
    else        s = Bh + (bTile0 + (long)(t - TA) * tkB) * 512;
    srcs[i] = s + c * 512 + laneOff;
    dsts[i] = lds + t2 * 512;
  }

  f32x4 acc[MREP][NREP];
#pragma unroll
  for (int m = 0; m < MREP; ++m)
#pragma unroll
    for (int n = 0; n < NREP; ++n) acc[m][n] = {0.f, 0.f, 0.f, 0.f};

  const int fo = (kg * 16 + fr) * 8;
  const u16* sA_ = lds;
  const u16* sB_ = lds + TA * CH * 512;

  for (int kc = 0; kc < K / (32 * CH); ++kc) {
#pragma unroll
    for (int i = 0; i < NL2; ++i) {
      load_lds16(srcs[i], dsts[i]);
      srcs[i] += CH * 512;
    }
    __syncthreads();
#pragma unroll
    for (int c = 0; c < CH; ++c) {
      bf16x8 fah[MREP], fbh[NREP];
#pragma unroll
      for (int m = 0; m < MREP; ++m)
        fah[m] = *(const bf16x8*)(sA_ + ((wr * MREP + m) * CH + c) * 512 + fo);
#pragma unroll
      for (int n = 0; n < NREP; ++n)
        fbh[n] = *(const bf16x8*)(sB_ + ((wc * NREP + n) * CH + c) * 512 + fo);
#pragma unroll
      for (int m = 0; m < MREP; ++m)
#pragma unroll
        for (int n = 0; n < NREP; ++n)
          acc[m][n] = __builtin_amdgcn_mfma_f32_16x16x32_bf16(fah[m], fbh[n], acc[m][n], 0, 0, 0);
    }
    __syncthreads();
  }
  if constexpr (OUTMODE == 3) {
#pragma unroll
    for (int n = 0; n < NREP; ++n) {
      const int col = col0 + (wc * NREP + n) * 16 + fr;
      const float bv = bias[col];
      const int k3 = (col >> 3) & 3;
      const int k7 = col & 7;
#pragma unroll
      for (int m = 0; m < MREP; ++m)
#pragma unroll
        for (int r = 0; r < 4; ++r) {
          const int row = row0 + (wr * MREP + m) * 16 + kg * 4 + r;
          const float v = fmaxf(acc[m][n][r] + bv, 0.f);
          const long off = ((long)(row >> 4) * tkC + (col >> 5)) * 512 + k3 * 128 + (row & 15) * 8 + k7;
          th[off] = f2bf(v);
        }
    }
  } else if constexpr (OUTMODE == 4) {
    __shared__ float rsum[BM];
    for (int i = tid; i < BM; i += 256) rsum[i] = 0.f;
    __syncthreads();
    float rs[MREP][4];
#pragma unroll
    for (int m = 0; m < MREP; ++m)
#pragma unroll
      for (int r = 0; r < 4; ++r) rs[m][r] = 0.f;
#pragma unroll
    for (int n = 0; n < NREP; ++n) {
      const int col = col0 + (wc * NREP + n) * 16 + fr;
      const float bv = bias[col];
#pragma unroll
      for (int m = 0; m < MREP; ++m)
#pragma unroll
        for (int r = 0; r < 4; ++r) {
          const long row = row0 + (wr * MREP + m) * 16 + kg * 4 + r;
          const float e = __expf(acc[m][n][r] + bv);
          C[row * ldc + col] = e;
          rs[m][r] += e;
        }
    }
#pragma unroll
    for (int m = 0; m < MREP; ++m)
#pragma unroll
      for (int r = 0; r < 4; ++r) {
#pragma unroll
        for (int off = 1; off < 16; off <<= 1) rs[m][r] += __shfl_xor(rs[m][r], off, 16);
        if (fr == 0) atomicAdd(&rsum[(wr * MREP + m) * 16 + kg * 4 + r], rs[m][r]);
      }
    __syncthreads();
    for (int i = tid; i < BM; i += 256)
      partial[(long)(row0 + i) * 256 + blockIdx.y] = rsum[i];
  } else if constexpr (OUTMODE == 5) {
    // fused QKV prep. Global col decides section: 0..1023 Q (rope*0.125), 1024..2047 K (rope),
    // 2048..3071 V (transpose-tiled). BN block lies entirely in one section.
    const int gc0 = colBase + col0;
    const int sect = gc0 >> 10;
    u16* T = qkvT + (long)sect * 2097152;   // each tensor: 64 z * 32768
#pragma unroll
    for (int n = 0; n < NREP; ++n) {
      const int gcol = gc0 + (wc * NREP + n) * 16 + fr;
      const float bv = bias[gcol];
      const int hc = (gcol & 1023) >> 6;
      const int d = gcol & 63;
#pragma unroll
      for (int m = 0; m < MREP; ++m)
#pragma unroll
        for (int r = 0; r < 4; ++r) {
          const int row = row0 + (wr * MREP + m) * 16 + kg * 4 + r;
          const int b = row >> 9, s = row & 511;
          const float v = acc[m][n][r] + bv;
          const long zb = (long)(b * 16 + hc) * 32768;
          if (sect < 2) {
            const float vp = __shfl_xor(v, 1);
            const int i2 = d >> 1;
            const float cc = cosT[s * 32 + i2], ss = sinT[s * 32 + i2];
            float ro = (d & 1) ? (vp * ss + v * cc) : (v * cc - vp * ss);
            if (sect == 0) ro *= 0.125f;
            const long off = zb + ((long)(s >> 4) * 2 + (d >> 5)) * 512 +
                             ((d >> 3) & 3) * 128 + (s & 15) * 8 + (d & 7);
            T[off] = f2bf(ro);
          } else {
            const long off = zb + ((long)(d >> 4) * 16 + (s >> 5)) * 512 +
                             ((s >> 3) & 3) * 128 + (d & 15) * 8 + (s & 7);
            T[off] = f2bf(v);
          }
        }
    }
  } else {
#pragma unroll
    for (int n = 0; n < NREP; ++n) {
      const int col = col0 + (wc * NREP + n) * 16 + fr;
      const float bv = bias ? bias[col] : 0.f;
#pragma unroll
      for (int m = 0; m < MREP; ++m)
#pragma unroll
        for (int r = 0; r < 4; ++r) {
          const long row = row0 + (wr * MREP + m) * 16 + kg * 4 + r;
          C[row * ldc + col] = acc[m][n][r] + bv;
        }
    }
  }
}

// ---- flash attention: per block (64 q-rows, z=(b,h)); Q pre-scaled by 0.125.
// KVBLK=128 (32 KV tiles/iter, half the barriers). No online max (scores O(1)-bounded);
// masked -> -30 sentinel (uniform on all-masked rows). ----
__global__ __launch_bounds__(256) void flash_kernel(
    const u16* __restrict__ Qt, const u16* __restrict__ Kt,
    const u16* __restrict__ Vt, const int* __restrict__ tok,
    u16* __restrict__ Oh, int causal)
{
  __shared__ __align__(16) u16 sKV[32 * 512];   // K tiles 0..15, V tiles 16..31
  __shared__ __align__(16) u16 sP[16 * 512];    // P tiles / epilogue staging
  const int tid = threadIdx.x, wid = tid >> 6, lane = tid & 63;
  const int fr = lane & 15, kg = lane >> 4;
  const int qblk = blockIdx.x, z = blockIdx.y;  // qblk: 64 rows
  const int b = z >> 4, h = z & 15;
  const long zbase = (long)z * 32768;
  const int fo = (kg * 16 + fr) * 8;
  const int laneOff = lane * 8;
  int kb2lim = 4;
  if (causal && tok[b * 512] != 0) kb2lim = (qblk + 2) >> 1;
  bf16x8 qf[2];
#pragma unroll
  for (int kc = 0; kc < 2; ++kc)
    qf[kc] = *(const bf16x8*)(Qt + zbase + ((long)(qblk * 4 + wid) * 2 + kc) * 512 + fo);
  f32x4 acc_o[4];
  float lp[4];
#pragma unroll
  for (int n = 0; n < 4; ++n) acc_o[n] = {0.f, 0.f, 0.f, 0.f};
#pragma unroll
  for (int r = 0; r < 4; ++r) lp[r] = 0.f;

  for (int kb2 = 0; kb2 < kb2lim; ++kb2) {
    __syncthreads();   // previous PV reads of sKV/sP complete
#pragma unroll
    for (int i = 0; i < 8; ++i) {
      const int t = wid + i * 4;
      const u16* src;
      if (t < 16) {
        src = Kt + zbase + (long)((kb2 * 8 + (t >> 1)) * 2 + (t & 1)) * 512;
      } else {
        const int u = t - 16;
        src = Vt + zbase + (long)((u >> 2) * 16 + kb2 * 4 + (u & 3)) * 512;
      }
      load_lds16(src + laneOff, sKV + t * 512);
    }
    __syncthreads();   // staging complete
    f32x4 s4[8];
#pragma unroll
    for (int n = 0; n < 8; ++n) s4[n] = {0.f, 0.f, 0.f, 0.f};
    __builtin_amdgcn_s_setprio(1);
#pragma unroll
    for (int kc = 0; kc < 2; ++kc)
#pragma unroll
      for (int n = 0; n < 8; ++n) {
        const bf16x8 kf = *(const bf16x8*)(sKV + (n * 2 + kc) * 512 + fo);
        s4[n] = __builtin_amdgcn_mfma_f32_16x16x32_bf16(qf[kc], kf, s4[n], 0, 0, 0);
      }
    __builtin_amdgcn_s_setprio(0);
    int tmask[8];
#pragma unroll
    for (int n = 0; n < 8; ++n) tmask[n] = tok[b * 512 + kb2 * 128 + n * 16 + fr];
#pragma unroll
    for (int r = 0; r < 4; ++r) {
      const int q = qblk * 64 + wid * 16 + kg * 4 + r;
#pragma unroll
      for (int n = 0; n < 8; ++n) {
        const int kcol = kb2 * 128 + n * 16 + fr;
        const bool ok = (tmask[n] != 0) && (!causal || kcol <= q);
        const float p = __expf(ok ? s4[n][r] : -30.0f);
        lp[r] += p;
        sP[(wid * 4 + (n >> 1)) * 512 + ((n & 1) * 2 + (fr >> 3)) * 128 +
           (kg * 4 + r) * 8 + (fr & 7)] = f2bf(p);
      }
    }
    __syncthreads();   // P visible
    __builtin_amdgcn_s_setprio(1);
#pragma unroll
    for (int kc2 = 0; kc2 < 4; ++kc2) {
      const bf16x8 pf = *(const bf16x8*)(sP + (wid * 4 + kc2) * 512 + fo);
#pragma unroll
      for (int n = 0; n < 4; ++n) {
        const bf16x8 vf = *(const bf16x8*)(sKV + (16 + n * 4 + kc2) * 512 + fo);
        acc_o[n] = __builtin_amdgcn_mfma_f32_16x16x32_bf16(pf, vf, acc_o[n], 0, 0, 0);
      }
    }
    __builtin_amdgcn_s_setprio(0);
  }
#pragma unroll
  for (int r = 0; r < 4; ++r) {
    float s = lp[r];
#pragma unroll
    for (int off = 1; off < 16; off <<= 1) s += __shfl_xor(s, off, 16);
    const float inv = 1.0f / s;
#pragma unroll
    for (int n = 0; n < 4; ++n) acc_o[n][r] *= inv;
  }
  __syncthreads();
#pragma unroll
  for (int n = 0; n < 4; ++n)
#pragma unroll
    for (int r = 0; r < 4; ++r) {
      const int k3 = (n & 1) * 2 + (fr >> 3);
      sP[(wid * 2 + (n >> 1)) * 512 + k3 * 128 + (kg * 4 + r) * 8 + (fr & 7)] = f2bf(acc_o[n][r]);
    }
  __syncthreads();
  const long rbg = (long)b * 32 + qblk * 4 + wid;
#pragma unroll
  for (int i = 0; i < 2; ++i) {
    const long off = (rbg * 32 + h * 2 + i) * 512 + laneOff;
    *(uint4*)(Oh + off) = *(const uint4*)(sP + (wid * 2 + i) * 512 + laneOff);
  }
}

// ---- out = LayerNorm(X + R)*g + be ; writes fp32 + tiled hi ----
__global__ __launch_bounds__(256) void ln_fused_kernel(
    const float* __restrict__ X, const float* __restrict__ R,
    const float* __restrict__ g, const float* __restrict__ be,
    float* __restrict__ Out, u16* __restrict__ th)
{
  __shared__ float red[8];
  const int tid = threadIdx.x;
  const long row = blockIdx.x;
  const int k0 = tid * 4;
  const float4 xv = *(const float4*)(X + row * DMODEL + k0);
  const float4 rv = *(const float4*)(R + row * DMODEL + k0);
  const float v0 = xv.x + rv.x, v1 = xv.y + rv.y, v2 = xv.z + rv.z, v3 = xv.w + rv.w;
  float s = waveSum((v0 + v1) + (v2 + v3));
  const int wv = tid >> 6, ln = tid & 63;
  if (ln == 0) red[wv] = s;
  __syncthreads();
  const float mu = (red[0] + red[1] + red[2] + red[3]) * (1.0f / DMODEL);
  const float d0 = v0 - mu, d1 = v1 - mu, d2 = v2 - mu, d3 = v3 - mu;
  float sq = waveSum(d0 * d0 + d1 * d1 + d2 * d2 + d3 * d3);
  if (ln == 0) red[4 + wv] = sq;
  __syncthreads();
  const float var = (red[4] + red[5] + red[6] + red[7]) * (1.0f / DMODEL);
  const float rstd = 1.0f / sqrtf(var + 1e-5f);
  const float4 gv = *(const float4*)(g + k0);
  const float4 bv = *(const float4*)(be + k0);
  float4 o;
  o.x = d0 * rstd * gv.x + bv.x;
  o.y = d1 * rstd * gv.y + bv.y;
  o.z = d2 * rstd * gv.z + bv.z;
  o.w = d3 * rstd * gv.w + bv.w;
  *(float4*)(Out + row * DMODEL + k0) = o;
  const long off = ((row >> 4) * 32 + (k0 >> 5)) * 512 +
                   (long)(((k0 & 31) >> 3)) * 128 + (row & 15) * 8 + (k0 & 7);
  uint2 uh;
  uh.x = (unsigned)f2bf(o.x) | ((unsigned)f2bf(o.y) << 16);
  uh.y = (unsigned)f2bf(o.z) | ((unsigned)f2bf(o.w) << 16);
  *(uint2*)(th + off) = uh;
}

// ---- vocab normalize: P holds exp'd logits; partial[row][250] block sums ----
__global__ __launch_bounds__(256) void vocab_norm_kernel(
    float* __restrict__ P, const float* __restrict__ partial)
{
  __shared__ float red[4];
  const int tid = threadIdx.x;
  const long row = blockIdx.x;
  float s = (tid < 250) ? partial[row * 256 + tid] : 0.f;
  s = waveSum(s);
  const int wv = tid >> 6, ln = tid & 63;
  if (ln == 0) red[wv] = s;
  __syncthreads();
  const float inv = 1.0f / (red[0] + red[1] + red[2] + red[3]);
  float4* p = (float4*)(P + row * VOCAB);
  for (int i = tid; i < VOCAB / 4; i += 256) {
    float4 v = p[i];
    v.x *= inv; v.y *= inv; v.z *= inv; v.w *= inv;
    p[i] = v;
  }
}

extern "C" void kernel_launch(void* const* d_in, const int* in_sizes, int n_in,
                              void* d_out, int out_size, void* d_ws, size_t ws_size,
                              hipStream_t stream)
{
  (void)in_sizes; (void)n_in; (void)out_size; (void)ws_size;
  const int* src = (const int*)d_in[0];
  const int* tgt = (const int*)d_in[1];
  const float* enc_emb = (const float*)d_in[2];
  const float* dec_emb = (const float*)d_in[3];
  const float* eWq = (const float*)d_in[4];
  const float* eWk = (const float*)d_in[5];
  const float* eWv = (const float*)d_in[6];
  const float* eWo = (const float*)d_in[7];
  const float* eBq = (const float*)d_in[8];
  const float* eBk = (const float*)d_in[9];
  const float* eBv = (const float*)d_in[10];
  const float* eBo = (const float*)d_in[11];
  const float* eL1g = (const float*)d_in[12];
  const float* eL1b = (const float*)d_in[13];
  const float* eL2g = (const float*)d_in[14];
  const float* eL2b = (const float*)d_in[15];
  const float* eF1  = (const float*)d_in[16];
  const float* eF1b = (const float*)d_in[17];
  const float* eF2  = (const float*)d_in[18];
  const float* eF2b = (const float*)d_in[19];
  const float* dsWq = (const float*)d_in[20];
  const float* dsWk = (const float*)d_in[21];
  const float* dsWv = (const float*)d_in[22];
  const float* dsWo = (const float*)d_in[23];
  const float* dcWq = (const float*)d_in[24];
  const float* dcWk = (const float*)d_in[25];
  const float* dcWv = (const float*)d_in[26];
  const float* dcWo = (const float*)d_in[27];
  const float* dsBq = (const float*)d_in[28];
  const float* dsBk = (const float*)d_in[29];
  const float* dsBv = (const float*)d_in[30];
  const float* dsBo = (const float*)d_in[31];
  const float* dcBq = (const float*)d_in[32];
  const float* dcBk = (const float*)d_in[33];
  const float* dcBv = (const float*)d_in[34];
  const float* dcBo = (const float*)d_in[35];
  const float* dL1g = (const float*)d_in[36];
  const float* dL2g = (const float*)d_in[37];
  const float* dL3g = (const float*)d_in[38];
  const float* dL1b = (const float*)d_in[39];
  const float* dL2b = (const float*)d_in[40];
  const float* dL3b = (const float*)d_in[41];
  const float* dF1  = (const float*)d_in[42];
  const float* dF1b = (const float*)d_in[43];
  const float* dF2  = (const float*)d_in[44];
  const float* dF2b = (const float*)d_in[45];
  const float* fW   = (const float*)d_in[46];
  const float* fb   = (const float*)d_in[47];

  // ---- workspace carve (~102 MiB) ----
  char* base = (char*)d_ws;
  auto alloc = [&](size_t bytes) { char* p = base; base += (bytes + 1023) & ~(size_t)1023; return p; };
  float* cosT   = (float*)alloc(SEQLEN * 32 * 4);
  float* sinT   = (float*)alloc(SEQLEN * 32 * 4);
  float* fusedB = (float*)alloc(3072 * 4);
  float* xb  = (float*)alloc((long)MROWS * DMODEL * 4);
  float* yb  = (float*)alloc((long)MROWS * DMODEL * 4);
  float* pb  = (float*)alloc((long)MROWS * DMODEL * 4);
  u16*   mt  = (u16*)alloc((long)MROWS * DMODEL * 2);   // encoder memory, tiled hi
  char* rA = base;
  u16* sth  = (u16*)(rA + 0 * MiB);     // stream tiled hi (4 MiB)
  // attention set
  u16* aWh  = (u16*)(rA + 8 * MiB);     // 6 MiB (3072x1024 hi)
  u16* qkvT = (u16*)(rA + 14 * MiB);    // 12 MiB: Qt +0, Kt +2M elems, Vt +4M elems
  u16* ath  = (u16*)(rA + 26 * MiB);    // 4 MiB
  u16* oWh  = (u16*)(rA + 30 * MiB);    // 2 MiB (ends 32)
  // FFN set (attention buffers dead)
  u16* f1h = (u16*)(rA + 8 * MiB);      // 8 MiB (4096x1024)
  u16* f2h = (u16*)(rA + 16 * MiB);     // 8 MiB (1024x4096)
  u16* fth = (u16*)(rA + 24 * MiB);     // 16 MiB (2048x4096 hi)
  // vocab set
  u16* vh  = (u16*)(rA + 8 * MiB);      // 62.5 MiB (32000x1024), ends 70.5
  float* vpart = (float*)(rA + 71 * MiB); // 2 MiB (2048x256 row partials)
  u16* Qt = qkvT;
  u16* Kt = qkvT + 2097152;
  u16* Vt = qkvT + 2 * 2097152;

  const long DD = (long)DMODEL * DMODEL;
  const long DF = (long)DMODEL * DFFN;

  rope_tab_kernel<<<(SEQLEN * 32) / 256, 256, 0, stream>>>(cosT, sinT);

  auto attention = [&](int self, const float* Wq, const float* Bq,
                       const float* Wk, const float* Bk,
                       const float* Wv, const float* Bv,
                       const float* Wo, const float* Bo,
                       const int* tok, int causal) {
    wconv_attn_kernel<<<dim3(32, 16, 4), 256, 0, stream>>>(
        Wq, Wk, Wv, Wo, Bq, Bk, Bv, aWh, oWh, fusedB);
    if (self) {
      gemm_t_kernel<128, 64, 5, 2><<<dim3(16, 48), 256, 0, stream>>>(
          sth, aWh, fusedB, nullptr, nullptr, nullptr, qkvT, cosT, sinT,
          1024, 32, 32, 0, 0, 0);
    } else {
      gemm_t_kernel<64, 64, 5, 2><<<dim3(32, 16), 256, 0, stream>>>(
          sth, aWh, fusedB, nullptr, nullptr, nullptr, qkvT, cosT, sinT,
          1024, 32, 32, 0, 0, 0);
      gemm_t_kernel<128, 64, 5, 2><<<dim3(16, 32), 256, 0, stream>>>(
          mt, aWh + (long)64 * 32 * 512, fusedB, nullptr, nullptr, nullptr, qkvT, cosT, sinT,
          1024, 32, 32, 0, 0, 1024);
    }
    flash_kernel<<<dim3(8, 64), 256, 0, stream>>>(Qt, Kt, Vt, tok, ath, causal);
    gemm_t_kernel<64, 64, 0, 2><<<dim3(32, 16), 256, 0, stream>>>(
        ath, oWh, Bo, pb, nullptr, nullptr, nullptr, nullptr, nullptr,
        1024, 32, 32, 1024, 0, 0);
  };

  auto ffn = [&](const float* W1, const float* B1, const float* W2, const float* B2) {
    wconv_ffn_kernel<<<4096, 256, 0, stream>>>(W1, W2, f1h, f2h);
    gemm_t_kernel<128, 64, 3, 2><<<dim3(16, 64), 256, 0, stream>>>(
        sth, f1h, B1, nullptr, fth, nullptr, nullptr, nullptr, nullptr,
        1024, 32, 32, 0, 128, 0);
    gemm_t_kernel<64, 64, 0, 4><<<dim3(32, 16), 256, 0, stream>>>(
        fth, f2h, B2, pb, nullptr, nullptr, nullptr, nullptr, nullptr,
        4096, 128, 128, 1024, 0, 0);
  };

  // -------- encoder --------
  embed_t_kernel<<<MROWS, 256, 0, stream>>>(src, enc_emb, xb, sth);
  for (int l = 0; l < NLAYER; ++l) {
    attention(1, eWq + l * DD, eBq + l * DMODEL, eWk + l * DD, eBk + l * DMODEL,
              eWv + l * DD, eBv + l * DMODEL, eWo + l * DD, eBo + l * DMODEL, src, 0);
    ln_fused_kernel<<<MROWS, 256, 0, stream>>>(xb, pb, eL1g + l * DMODEL, eL1b + l * DMODEL,
                                               xb, sth);
    ffn(eF1 + l * DF, eF1b + l * DFFN, eF2 + l * DF, eF2b + l * DMODEL);
    ln_fused_kernel<<<MROWS, 256, 0, stream>>>(xb, pb, eL2g + l * DMODEL, eL2b + l * DMODEL,
                                               xb, (l == NLAYER - 1) ? mt : sth);
  }
  // -------- decoder --------
  embed_t_kernel<<<MROWS, 256, 0, stream>>>(tgt, dec_emb, yb, sth);
  for (int l = 0; l < NLAYER; ++l) {
    attention(1, dsWq + l * DD, dsBq + l * DMODEL, dsWk + l * DD, dsBk + l * DMODEL,
              dsWv + l * DD, dsBv + l * DMODEL, dsWo + l * DD, dsBo + l * DMODEL, tgt, 1);
    ln_fused_kernel<<<MROWS, 256, 0, stream>>>(yb, pb, dL1g + l * DMODEL, dL1b + l * DMODEL,
                                               yb, sth);
    attention(0, dcWq + l * DD, dcBq + l * DMODEL, dcWk + l * DD, dcBk + l * DMODEL,
              dcWv + l * DD, dcBv + l * DMODEL, dcWo + l * DD, dcBo + l * DMODEL, src, 0);
    ln_fused_kernel<<<MROWS, 256, 0, stream>>>(yb, pb, dL2g + l * DMODEL, dL2b + l * DMODEL,
                                               yb, sth);
    ffn(dF1 + l * DF, dF1b + l * DFFN, dF2 + l * DF, dF2b + l * DMODEL);
    ln_fused_kernel<<<MROWS, 256, 0, stream>>>(yb, pb, dL3g + l * DMODEL, dL3b + l * DMODEL,
                                               yb, sth);
  }
  // -------- final projection (exp fused) + normalize --------
  float* outp = (float*)d_out;
  wconv_kernel<<<dim3(32, 500), 256, 0, stream>>>(fW, vh, 1024, VOCAB, 0);
  gemm_t_kernel<128, 128, 4, 2><<<dim3(16, 250), 256, 0, stream>>>(
      sth, vh, fb, outp, nullptr, vpart, nullptr, nullptr, nullptr,
      1024, 32, 32, VOCAB, 0, 0);
  vocab_norm_kernel<<<MROWS, 256, 0, stream>>>(outp, vpart);
}

// Round 13
// 2673.171 us; speedup vs baseline: 1.1234x; 1.0162x over previous
//
#include <hip/hip_runtime.h>
#include <math.h>

#define NLAYER 6
#define DMODEL 1024
#define NHEAD  16
#define DFFN   4096
#define VOCAB  32000
#define NBATCH 4
#define SEQLEN 512
#define HDIM   64
#define MROWS  (NBATCH*SEQLEN)
#define MiB    (1024L*1024L)

typedef __attribute__((ext_vector_type(8))) short bf16x8;
typedef __attribute__((ext_vector_type(4))) float f32x4;
typedef unsigned short u16;

__device__ __forceinline__ float waveSum(float v) {
#pragma unroll
  for (int off = 32; off > 0; off >>= 1) v += __shfl_xor(v, off);
  return v;
}
__device__ __forceinline__ u16 f2bf(float x) {
  unsigned u = __float_as_uint(x);
  u += 0x7FFFu + ((u >> 16) & 1u);   // RNE
  return (u16)(u >> 16);
}
__device__ __forceinline__ float bf2f(u16 h) {
  return __uint_as_float((unsigned)h << 16);
}
__device__ __forceinline__ void load_lds16(const u16* src, u16* dst) {
  __builtin_amdgcn_global_load_lds(
      (const __attribute__((address_space(1))) unsigned int*)src,
      (__attribute__((address_space(3))) unsigned int*)dst, 16, 0, 0);
}

// Tiled bf16 layout: tile(rb,kc) of a [R][K] matrix = 16 rows x 32 K (1 KiB).
// base = (rb*(K/32)+kc)*512 ; elem(row,k) = ((k>>3)&3)*128 + (row&15)*8 + (k&7)

// ---- embedding gather + fp32 out + tiled hi ----
__global__ __launch_bounds__(256) void embed_t_kernel(
    const int* __restrict__ tok, const float* __restrict__ emb,
    float* __restrict__ out, u16* __restrict__ th)
{
  const long row = blockIdx.x;
  const int t = tok[row];
  const int k0 = threadIdx.x * 4;
  const float4 v = *(const float4*)(emb + (long)t * DMODEL + k0);
  *(float4*)(out + row * DMODEL + k0) = v;
  const long off = ((row >> 4) * 32 + (k0 >> 5)) * 512 +
                   (long)(((k0 & 31) >> 3)) * 128 + (row & 15) * 8 + (k0 & 7);
  uint2 uh;
  uh.x = (unsigned)f2bf(v.x) | ((unsigned)f2bf(v.y) << 16);
  uh.y = (unsigned)f2bf(v.z) | ((unsigned)f2bf(v.w) << 16);
  *(uint2*)(th + off) = uh;
}

// ---- rope tables ----
__global__ __launch_bounds__(256) void rope_tab_kernel(float* __restrict__ cosT, float* __restrict__ sinT)
{
  const int idx = blockIdx.x * 256 + threadIdx.x;   // < SEQLEN*32
  const int s = idx >> 5, i = idx & 31;
  const float e = (float)(2 * i) / 64.0f;
  const float inv = 1.0f / powf(10000.0f, e);
  const float ang = (float)s * inv;
  cosT[idx] = cosf(ang);
  sinT[idx] = sinf(ang);
}

// ---- generic weight convert: W[K][ldN] fp32 slice -> tiled bf16 hi ----
__global__ __launch_bounds__(256) void wconv_kernel(
    const float* __restrict__ W, u16* __restrict__ Wh,
    int K, int ldN, int nbase)
{
  __shared__ float tile[32][68];
  const int t = threadIdx.x;
  const int k0 = blockIdx.x * 32, n0 = blockIdx.y * 64;
  {
    const int r = t >> 3, c = (t & 7) * 8;
    const float* wp = W + (long)(k0 + r) * ldN + nbase + n0 + c;
    *(float4*)&tile[r][c]     = *(const float4*)wp;
    *(float4*)&tile[r][c + 4] = *(const float4*)(wp + 4);
  }
  __syncthreads();
  const int fr = t & 15, kg = (t >> 4) & 3, nb = t >> 6;
  const int n = nb * 16 + fr;
  unsigned ph[4];
#pragma unroll
  for (int i = 0; i < 4; ++i) {
    const float x0 = tile[kg * 8 + 2 * i][n];
    const float x1 = tile[kg * 8 + 2 * i + 1][n];
    ph[i] = (unsigned)f2bf(x0) | ((unsigned)f2bf(x1) << 16);
  }
  const int tk = K >> 5;
  const long off = ((long)(n0 / 16 + nb) * tk + (k0 >> 5)) * 512 + kg * 128 + fr * 8;
  *(uint4*)(Wh + off) = make_uint4(ph[0], ph[1], ph[2], ph[3]);
}

// ---- FFN weight convert: W1 and W2 -> tiled hi, single launch ----
__global__ __launch_bounds__(256) void wconv_ffn_kernel(
    const float* __restrict__ W1, const float* __restrict__ W2,
    u16* __restrict__ f1h, u16* __restrict__ f2h)
{
  __shared__ float tile[32][68];
  const int bx = blockIdx.x, t = threadIdx.x;
  const float* W; u16* out; int K, ldN, k0, n0;
  if (bx < 2048) { W = W1; out = f1h; K = 1024; ldN = 4096; k0 = (bx & 31) * 32;  n0 = (bx >> 5) * 64; }
  else { const int xx = bx - 2048; W = W2; out = f2h; K = 4096; ldN = 1024; k0 = (xx & 127) * 32; n0 = (xx >> 7) * 64; }
  {
    const int r = t >> 3, c = (t & 7) * 8;
    const float* wp = W + (long)(k0 + r) * ldN + n0 + c;
    *(float4*)&tile[r][c]     = *(const float4*)wp;
    *(float4*)&tile[r][c + 4] = *(const float4*)(wp + 4);
  }
  __syncthreads();
  const int fr = t & 15, kg = (t >> 4) & 3, nb = t >> 6;
  const int n = nb * 16 + fr;
  unsigned ph[4];
#pragma unroll
  for (int i = 0; i < 4; ++i) {
    const float x0 = tile[kg * 8 + 2 * i][n];
    const float x1 = tile[kg * 8 + 2 * i + 1][n];
    ph[i] = (unsigned)f2bf(x0) | ((unsigned)f2bf(x1) << 16);
  }
  const int tk = K >> 5;
  const long off = ((long)(n0 / 16 + nb) * tk + (k0 >> 5)) * 512 + kg * 128 + fr * 8;
  *(uint4*)(out + off) = make_uint4(ph[0], ph[1], ph[2], ph[3]);
}

// ---- attention weight convert (z=0..2 QKV->aWh hi, z=3 O->oWh hi) + fused bias copy ----
__global__ __launch_bounds__(256) void wconv_attn_kernel(
    const float* __restrict__ Wq, const float* __restrict__ Wk,
    const float* __restrict__ Wv, const float* __restrict__ Wo,
    const float* __restrict__ Bq, const float* __restrict__ Bk,
    const float* __restrict__ Bv,
    u16* __restrict__ aWh, u16* __restrict__ oWh, float* __restrict__ fusedB)
{
  __shared__ float tile[32][68];
  const int zz = blockIdx.z;
  const float* W = (zz == 0) ? Wq : (zz == 1) ? Wk : (zz == 2) ? Wv : Wo;
  u16* Wh = (zz < 3) ? aWh : oWh;
  const int obase = (zz < 3) ? zz * 1024 : 0;
  const int t = threadIdx.x;
  const int k0 = blockIdx.x * 32, n0 = blockIdx.y * 64;
  if (zz < 3 && blockIdx.x == 0 && blockIdx.y < 4) {
    const float* B = (zz == 0) ? Bq : (zz == 1) ? Bk : Bv;
    fusedB[zz * 1024 + blockIdx.y * 256 + t] = B[blockIdx.y * 256 + t];
  }
  {
    const int r = t >> 3, c = (t & 7) * 8;
    const float* wp = W + (long)(k0 + r) * 1024 + n0 + c;
    *(float4*)&tile[r][c]     = *(const float4*)wp;
    *(float4*)&tile[r][c + 4] = *(const float4*)(wp + 4);
  }
  __syncthreads();
  const int fr = t & 15, kg = (t >> 4) & 3, nb = t >> 6;
  const int n = nb * 16 + fr;
  unsigned ph[4];
#pragma unroll
  for (int i = 0; i < 4; ++i) {
    const float x0 = tile[kg * 8 + 2 * i][n];
    const float x1 = tile[kg * 8 + 2 * i + 1][n];
    ph[i] = (unsigned)f2bf(x0) | ((unsigned)f2bf(x1) << 16);
  }
  const long off = ((long)((obase + n0) / 16 + nb) * 32 + (k0 >> 5)) * 512 + kg * 128 + fr * 8;
  *(uint4*)(Wh + off) = make_uint4(ph[0], ph[1], ph[2], ph[3]);
}

// ---- tiled GEMM: C = A @ B^T (all bf16-hi). CH = 32-K chunks per barrier.
// 4 waves (2x2). OUTMODE: 0 bias->C, 3 bias+relu->tiled hi (LDS-staged coalesced),
//          4 exp(bias+acc)->C (nontemporal) + row partials,
//          5 fused QKV prep (LDS-staged coalesced): rope Q/K + V transpose -> qkvT. ----
template<int BM, int BN, int OUTMODE, int CH>
__global__ __launch_bounds__(256) void gemm_t_kernel(
    const u16* __restrict__ Ah, const u16* __restrict__ Bh,
    const float* __restrict__ bias, float* __restrict__ C,
    u16* __restrict__ th, float* __restrict__ partial,
    u16* __restrict__ qkvT, const float* __restrict__ cosT,
    const float* __restrict__ sinT,
    int K, int tkA, int tkB, long ldc, int tkC, int colBase)
{
  constexpr int TA = BM / 16;
  constexpr int TB = BN / 16;
  constexpr int MREP = BM / 32;
  constexpr int NREP = BN / 32;
  constexpr int NTILES2 = (TA + TB) * CH;
  constexpr int NL2 = NTILES2 / 4;
  constexpr int OT = (BM / 16) * (BN / 32);   // output tiles (16r x 32c each)
  __shared__ __align__(16) u16 lds[NTILES2 * 512];
  const int tid = threadIdx.x, wid = tid >> 6, lane = tid & 63;
  const int fr = lane & 15, kg = lane >> 4;
  const int wr = wid >> 1, wc = wid & 1;
  const int row0 = blockIdx.x * BM, col0 = blockIdx.y * BN;
  const long aTile0 = (long)(row0 >> 4) * tkA;
  const long bTile0 = (long)(col0 >> 4) * tkB;
  const int laneOff = lane * 8;

  const u16* srcs[NL2];
  u16* dsts[NL2];
#pragma unroll
  for (int i = 0; i < NL2; ++i) {
    const int t2 = wid + i * 4;
    const int t = t2 / CH, c = t2 % CH;
    const u16* s;
    if (t < TA) s = Ah + (aTile0 + (long)t * tkA) * 512;
    else        s = Bh + (bTile0 + (long)(t - TA) * tkB) * 512;
    srcs[i] = s + c * 512 + laneOff;
    dsts[i] = lds + t2 * 512;
  }

  f32x4 acc[MREP][NREP];
#pragma unroll
  for (int m = 0; m < MREP; ++m)
#pragma unroll
    for (int n = 0; n < NREP; ++n) acc[m][n] = {0.f, 0.f, 0.f, 0.f};

  const int fo = (kg * 16 + fr) * 8;
  const u16* sA_ = lds;
  const u16* sB_ = lds + TA * CH * 512;

  for (int kc = 0; kc < K / (32 * CH); ++kc) {
#pragma unroll
    for (int i = 0; i < NL2; ++i) {
      load_lds16(srcs[i], dsts[i]);
      srcs[i] += CH * 512;
    }
    __syncthreads();
#pragma unroll
    for (int c = 0; c < CH; ++c) {
      bf16x8 fah[MREP], fbh[NREP];
#pragma unroll
      for (int m = 0; m < MREP; ++m)
        fah[m] = *(const bf16x8*)(sA_ + ((wr * MREP + m) * CH + c) * 512 + fo);
#pragma unroll
      for (int n = 0; n < NREP; ++n)
        fbh[n] = *(const bf16x8*)(sB_ + ((wc * NREP + n) * CH + c) * 512 + fo);
#pragma unroll
      for (int m = 0; m < MREP; ++m)
#pragma unroll
        for (int n = 0; n < NREP; ++n)
          acc[m][n] = __builtin_amdgcn_mfma_f32_16x16x32_bf16(fah[m], fbh[n], acc[m][n], 0, 0, 0);
    }
    __syncthreads();
  }
  if constexpr (OUTMODE == 3) {
    // stage relu'd bf16 into LDS in tiled layout, then coalesced uint4 stores
    u16* stage = lds;
#pragma unroll
    for (int n = 0; n < NREP; ++n) {
      const int lcol = (wc * NREP + n) * 16 + fr;
      const float bv = bias[col0 + lcol];
      const int ct = lcol >> 5;
      const int k3 = (lcol >> 3) & 3;
      const int k7 = lcol & 7;
#pragma unroll
      for (int m = 0; m < MREP; ++m) {
        const int rt = wr * MREP + m;
#pragma unroll
        for (int r = 0; r < 4; ++r) {
          const int lr = kg * 4 + r;
          const float v = fmaxf(acc[m][n][r] + bv, 0.f);
          stage[(rt * (BN / 32) + ct) * 512 + k3 * 128 + lr * 8 + k7] = f2bf(v);
        }
      }
    }
    __syncthreads();
#pragma unroll
    for (int j = 0; j < OT * 64 / 256; ++j) {
      const int idx = j * 256 + tid;
      const int g = idx >> 6, q = idx & 63;
      const int rt = g / (BN / 32), ct = g % (BN / 32);
      const long gtile = ((long)(row0 >> 4) + rt) * tkC + (col0 >> 5) + ct;
      *(uint4*)(th + gtile * 512 + q * 8) = *(const uint4*)(stage + g * 512 + q * 8);
    }
  } else if constexpr (OUTMODE == 4) {
    __shared__ float rsum[BM];
    for (int i = tid; i < BM; i += 256) rsum[i] = 0.f;
    __syncthreads();
    float rs[MREP][4];
#pragma unroll
    for (int m = 0; m < MREP; ++m)
#pragma unroll
      for (int r = 0; r < 4; ++r) rs[m][r] = 0.f;
#pragma unroll
    for (int n = 0; n < NREP; ++n) {
      const int col = col0 + (wc * NREP + n) * 16 + fr;
      const float bv = bias[col];
#pragma unroll
      for (int m = 0; m < MREP; ++m)
#pragma unroll
        for (int r = 0; r < 4; ++r) {
          const long row = row0 + (wr * MREP + m) * 16 + kg * 4 + r;
          const float e = __expf(acc[m][n][r] + bv);
          __builtin_nontemporal_store(e, &C[row * ldc + col]);
          rs[m][r] += e;
        }
    }
#pragma unroll
    for (int m = 0; m < MREP; ++m)
#pragma unroll
      for (int r = 0; r < 4; ++r) {
#pragma unroll
        for (int off = 1; off < 16; off <<= 1) rs[m][r] += __shfl_xor(rs[m][r], off, 16);
        if (fr == 0) atomicAdd(&rsum[(wr * MREP + m) * 16 + kg * 4 + r], rs[m][r]);
      }
    __syncthreads();
    for (int i = tid; i < BM; i += 256)
      partial[(long)(row0 + i) * 256 + blockIdx.y] = rsum[i];
  } else if constexpr (OUTMODE == 5) {
    // fused QKV prep (BN must be 64). Section: 0..1023 Q (rope*0.125), 1024..2047 K (rope),
    // 2048..3071 V (transpose). Stage tile in LDS, then coalesced uint4 stores.
    const int gc0 = colBase + col0;
    const int sect = gc0 >> 10;
    u16* T = qkvT + (long)sect * 2097152;   // each tensor: 64 z * 32768
    u16* stage = lds;
    const int s0 = row0 & 511;
#pragma unroll
    for (int n = 0; n < NREP; ++n) {
      const int d = (wc * NREP + n) * 16 + fr;   // head-local col (BN=64, col0 aligned)
      const float bv = bias[gc0 + d];
#pragma unroll
      for (int m = 0; m < MREP; ++m)
#pragma unroll
        for (int r = 0; r < 4; ++r) {
          const int lrow = (wr * MREP + m) * 16 + kg * 4 + r;  // local s
          const float v = acc[m][n][r] + bv;
          if (sect < 2) {
            const float vp = __shfl_xor(v, 1);
            const int s = s0 + lrow;
            const float cc = cosT[s * 32 + (d >> 1)], ss = sinT[s * 32 + (d >> 1)];
            float ro = (d & 1) ? (vp * ss + v * cc) : (v * cc - vp * ss);
            if (sect == 0) ro *= 0.125f;
            stage[((lrow >> 4) * 2 + (d >> 5)) * 512 + ((d >> 3) & 3) * 128 +
                  (lrow & 15) * 8 + (d & 7)] = f2bf(ro);
          } else {
            stage[((d >> 4) * (BM / 32) + (lrow >> 5)) * 512 + ((lrow >> 3) & 3) * 128 +
                  (d & 15) * 8 + (lrow & 7)] = f2bf(v);
          }
        }
    }
    __syncthreads();
    const int b = row0 >> 9;
    const int hc = (gc0 & 1023) >> 6;
    const long zb = (long)(b * 16 + hc) * 32768;
#pragma unroll
    for (int j = 0; j < OT * 64 / 256; ++j) {
      const int idx = j * 256 + tid;
      const int g = idx >> 6, q = idx & 63;
      long gtile;
      if (sect < 2) {
        const int st = g >> 1, dt = g & 1;
        gtile = (long)((s0 >> 4) + st) * 2 + dt;
      } else {
        const int d4 = g / (BM / 32), s5 = g % (BM / 32);
        gtile = (long)d4 * 16 + (s0 >> 5) + s5;
      }
      *(uint4*)(T + zb + gtile * 512 + q * 8) = *(const uint4*)(stage + g * 512 + q * 8);
    }
  } else {
#pragma unroll
    for (int n = 0; n < NREP; ++n) {
      const int col = col0 + (wc * NREP + n) * 16 + fr;
      const float bv = bias ? bias[col] : 0.f;
#pragma unroll
      for (int m = 0; m < MREP; ++m)
#pragma unroll
        for (int r = 0; r < 4; ++r) {
          const long row = row0 + (wr * MREP + m) * 16 + kg * 4 + r;
          C[row * ldc + col] = acc[m][n][r] + bv;
        }
    }
  }
}

// ---- flash attention: per block (64 q-rows, z=(b,h)); Q pre-scaled by 0.125.
// KVBLK=128 (32 KV tiles/iter). No online max (scores O(1)-bounded);
// masked -> -30 sentinel (uniform on all-masked rows). ----
__global__ __launch_bounds__(256) void flash_kernel(
    const u16* __restrict__ Qt, const u16* __restrict__ Kt,
    const u16* __restrict__ Vt, const int* __restrict__ tok,
    u16* __restrict__ Oh, int causal)
{
  __shared__ __align__(16) u16 sKV[32 * 512];   // K tiles 0..15, V tiles 16..31
  __shared__ __align__(16) u16 sP[16 * 512];    // P tiles / epilogue staging
  const int tid = threadIdx.x, wid = tid >> 6, lane = tid & 63;
  const int fr = lane & 15, kg = lane >> 4;
  const int qblk = blockIdx.x, z = blockIdx.y;  // qblk: 64 rows
  const int b = z >> 4, h = z & 15;
  const long zbase = (long)z * 32768;
  const int fo = (kg * 16 + fr) * 8;
  const int laneOff = lane * 8;
  int kb2lim = 4;
  if (causal && tok[b * 512] != 0) kb2lim = (qblk + 2) >> 1;
  bf16x8 qf[2];
#pragma unroll
  for (int kc = 0; kc < 2; ++kc)
    qf[kc] = *(const bf16x8*)(Qt + zbase + ((long)(qblk * 4 + wid) * 2 + kc) * 512 + fo);
  f32x4 acc_o[4];
  float lp[4];
#pragma unroll
  for (int n = 0; n < 4; ++n) acc_o[n] = {0.f, 0.f, 0.f, 0.f};
#pragma unroll
  for (int r = 0; r < 4; ++r) lp[r] = 0.f;

  for (int kb2 = 0; kb2 < kb2lim; ++kb2) {
    __syncthreads();   // previous PV reads of sKV/sP complete
#pragma unroll
    for (int i = 0; i < 8; ++i) {
      const int t = wid + i * 4;
      const u16* src;
      if (t < 16) {
        src = Kt + zbase + (long)((kb2 * 8 + (t >> 1)) * 2 + (t & 1)) * 512;
      } else {
        const int u = t - 16;
        src = Vt + zbase + (long)((u >> 2) * 16 + kb2 * 4 + (u & 3)) * 512;
      }
      load_lds16(src + laneOff, sKV + t * 512);
    }
    __syncthreads();   // staging complete
    f32x4 s4[8];
#pragma unroll
    for (int n = 0; n < 8; ++n) s4[n] = {0.f, 0.f, 0.f, 0.f};
    __builtin_amdgcn_s_setprio(1);
#pragma unroll
    for (int kc = 0; kc < 2; ++kc)
#pragma unroll
      for (int n = 0; n < 8; ++n) {
        const bf16x8 kf = *(const bf16x8*)(sKV + (n * 2 + kc) * 512 + fo);
        s4[n] = __builtin_amdgcn_mfma_f32_16x16x32_bf16(qf[kc], kf, s4[n], 0, 0, 0);
      }
    __builtin_amdgcn_s_setprio(0);
    int tmask[8];
#pragma unroll
    for (int n = 0; n < 8; ++n) tmask[n] = tok[b * 512 + kb2 * 128 + n * 16 + fr];
#pragma unroll
    for (int r = 0; r < 4; ++r) {
      const int q = qblk * 64 + wid * 16 + kg * 4 + r;
#pragma unroll
      for (int n = 0; n < 8; ++n) {
        const int kcol = kb2 * 128 + n * 16 + fr;
        const bool ok = (tmask[n] != 0) && (!causal || kcol <= q);
        const float p = __expf(ok ? s4[n][r] : -30.0f);
        lp[r] += p;
        sP[(wid * 4 + (n >> 1)) * 512 + ((n & 1) * 2 + (fr >> 3)) * 128 +
           (kg * 4 + r) * 8 + (fr & 7)] = f2bf(p);
      }
    }
    __syncthreads();   // P visible
    __builtin_amdgcn_s_setprio(1);
#pragma unroll
    for (int kc2 = 0; kc2 < 4; ++kc2) {
      const bf16x8 pf = *(const bf16x8*)(sP + (wid * 4 + kc2) * 512 + fo);
#pragma unroll
      for (int n = 0; n < 4; ++n) {
        const bf16x8 vf = *(const bf16x8*)(sKV + (16 + n * 4 + kc2) * 512 + fo);
        acc_o[n] = __builtin_amdgcn_mfma_f32_16x16x32_bf16(pf, vf, acc_o[n], 0, 0, 0);
      }
    }
    __builtin_amdgcn_s_setprio(0);
  }
#pragma unroll
  for (int r = 0; r < 4; ++r) {
    float s = lp[r];
#pragma unroll
    for (int off = 1; off < 16; off <<= 1) s += __shfl_xor(s, off, 16);
    const float inv = 1.0f / s;
#pragma unroll
    for (int n = 0; n < 4; ++n) acc_o[n][r] *= inv;
  }
  __syncthreads();
#pragma unroll
  for (int n = 0; n < 4; ++n)
#pragma unroll
    for (int r = 0; r < 4; ++r) {
      const int k3 = (n & 1) * 2 + (fr >> 3);
      sP[(wid * 2 + (n >> 1)) * 512 + k3 * 128 + (kg * 4 + r) * 8 + (fr & 7)] = f2bf(acc_o[n][r]);
    }
  __syncthreads();
  const long rbg = (long)b * 32 + qblk * 4 + wid;
#pragma unroll
  for (int i = 0; i < 2; ++i) {
    const long off = (rbg * 32 + h * 2 + i) * 512 + laneOff;
    *(uint4*)(Oh + off) = *(const uint4*)(sP + (wid * 2 + i) * 512 + laneOff);
  }
}

// ---- out = LayerNorm(X + R)*g + be ; writes fp32 + tiled hi ----
__global__ __launch_bounds__(256) void ln_fused_kernel(
    const float* __restrict__ X, const float* __restrict__ R,
    const float* __restrict__ g, const float* __restrict__ be,
    float* __restrict__ Out, u16* __restrict__ th)
{
  __shared__ float red[8];
  const int tid = threadIdx.x;
  const long row = blockIdx.x;
  const int k0 = tid * 4;
  const float4 xv = *(const float4*)(X + row * DMODEL + k0);
  const float4 rv = *(const float4*)(R + row * DMODEL + k0);
  const float v0 = xv.x + rv.x, v1 = xv.y + rv.y, v2 = xv.z + rv.z, v3 = xv.w + rv.w;
  float s = waveSum((v0 + v1) + (v2 + v3));
  const int wv = tid >> 6, ln = tid & 63;
  if (ln == 0) red[wv] = s;
  __syncthreads();
  const float mu = (red[0] + red[1] + red[2] + red[3]) * (1.0f / DMODEL);
  const float d0 = v0 - mu, d1 = v1 - mu, d2 = v2 - mu, d3 = v3 - mu;
  float sq = waveSum(d0 * d0 + d1 * d1 + d2 * d2 + d3 * d3);
  if (ln == 0) red[4 + wv] = sq;
  __syncthreads();
  const float var = (red[4] + red[5] + red[6] + red[7]) * (1.0f / DMODEL);
  const float rstd = 1.0f / sqrtf(var + 1e-5f);
  const float4 gv = *(const float4*)(g + k0);
  const float4 bv = *(const float4*)(be + k0);
  float4 o;
  o.x = d0 * rstd * gv.x + bv.x;
  o.y = d1 * rstd * gv.y + bv.y;
  o.z = d2 * rstd * gv.z + bv.z;
  o.w = d3 * rstd * gv.w + bv.w;
  *(float4*)(Out + row * DMODEL + k0) = o;
  const long off = ((row >> 4) * 32 + (k0 >> 5)) * 512 +
                   (long)(((k0 & 31) >> 3)) * 128 + (row & 15) * 8 + (k0 & 7);
  uint2 uh;
  uh.x = (unsigned)f2bf(o.x) | ((unsigned)f2bf(o.y) << 16);
  uh.y = (unsigned)f2bf(o.z) | ((unsigned)f2bf(o.w) << 16);
  *(uint2*)(th + off) = uh;
}

// ---- vocab normalize: P holds exp'd logits; partial[row][250] block sums ----
__global__ __launch_bounds__(256) void vocab_norm_kernel(
    float* __restrict__ P, const float* __restrict__ partial)
{
  __shared__ float red[4];
  const int tid = threadIdx.x;
  const long row = blockIdx.x;
  float s = (tid < 250) ? partial[row * 256 + tid] : 0.f;
  s = waveSum(s);
  const int wv = tid >> 6, ln = tid & 63;
  if (ln == 0) red[wv] = s;
  __syncthreads();
  const float inv = 1.0f / (red[0] + red[1] + red[2] + red[3]);
  f32x4* p = (f32x4*)(P + row * VOCAB);
  for (int i = tid; i < VOCAB / 4; i += 256) {
    f32x4 v = p[i];
    v *= inv;
    __builtin_nontemporal_store(v, &p[i]);
  }
}

extern "C" void kernel_launch(void* const* d_in, const int* in_sizes, int n_in,
                              void* d_out, int out_size, void* d_ws, size_t ws_size,
                              hipStream_t stream)
{
  (void)in_sizes; (void)n_in; (void)out_size; (void)ws_size;
  const int* src = (const int*)d_in[0];
  const int* tgt = (const int*)d_in[1];
  const float* enc_emb = (const float*)d_in[2];
  const float* dec_emb = (const float*)d_in[3];
  const float* eWq = (const float*)d_in[4];
  const float* eWk = (const float*)d_in[5];
  const float* eWv = (const float*)d_in[6];
  const float* eWo = (const float*)d_in[7];
  const float* eBq = (const float*)d_in[8];
  const float* eBk = (const float*)d_in[9];
  const float* eBv = (const float*)d_in[10];
  const float* eBo = (const float*)d_in[11];
  const float* eL1g = (const float*)d_in[12];
  const float* eL1b = (const float*)d_in[13];
  const float* eL2g = (const float*)d_in[14];
  const float* eL2b = (const float*)d_in[15];
  const float* eF1  = (const float*)d_in[16];
  const float* eF1b = (const float*)d_in[17];
  const float* eF2  = (const float*)d_in[18];
  const float* eF2b = (const float*)d_in[19];
  const float* dsWq = (const float*)d_in[20];
  const float* dsWk = (const float*)d_in[21];
  const float* dsWv = (const float*)d_in[22];
  const float* dsWo = (const float*)d_in[23];
  const float* dcWq = (const float*)d_in[24];
  const float* dcWk = (const float*)d_in[25];
  const float* dcWv = (const float*)d_in[26];
  const float* dcWo = (const float*)d_in[27];
  const float* dsBq = (const float*)d_in[28];
  const float* dsBk = (const float*)d_in[29];
  const float* dsBv = (const float*)d_in[30];
  const float* dsBo = (const float*)d_in[31];
  const float* dcBq = (const float*)d_in[32];
  const float* dcBk = (const float*)d_in[33];
  const float* dcBv = (const float*)d_in[34];
  const float* dcBo = (const float*)d_in[35];
  const float* dL1g = (const float*)d_in[36];
  const float* dL2g = (const float*)d_in[37];
  const float* dL3g = (const float*)d_in[38];
  const float* dL1b = (const float*)d_in[39];
  const float* dL2b = (const float*)d_in[40];
  const float* dL3b = (const float*)d_in[41];
  const float* dF1  = (const float*)d_in[42];
  const float* dF1b = (const float*)d_in[43];
  const float* dF2  = (const float*)d_in[44];
  const float* dF2b = (const float*)d_in[45];
  const float* fW   = (const float*)d_in[46];
  const float* fb   = (const float*)d_in[47];

  // ---- workspace carve (~102 MiB) ----
  char* base = (char*)d_ws;
  auto alloc = [&](size_t bytes) { char* p = base; base += (bytes + 1023) & ~(size_t)1023; return p; };
  float* cosT   = (float*)alloc(SEQLEN * 32 * 4);
  float* sinT   = (float*)alloc(SEQLEN * 32 * 4);
  float* fusedB = (float*)alloc(3072 * 4);
  float* xb  = (float*)alloc((long)MROWS * DMODEL * 4);
  float* yb  = (float*)alloc((long)MROWS * DMODEL * 4);
  float* pb  = (float*)alloc((long)MROWS * DMODEL * 4);
  u16*   mt  = (u16*)alloc((long)MROWS * DMODEL * 2);   // encoder memory, tiled hi
  char* rA = base;
  u16* sth  = (u16*)(rA + 0 * MiB);     // stream tiled hi (4 MiB)
  // attention set
  u16* aWh  = (u16*)(rA + 8 * MiB);     // 6 MiB (3072x1024 hi)
  u16* qkvT = (u16*)(rA + 14 * MiB);    // 12 MiB: Qt +0, Kt +2M elems, Vt +4M elems
  u16* ath  = (u16*)(rA + 26 * MiB);    // 4 MiB
  u16* oWh  = (u16*)(rA + 30 * MiB);    // 2 MiB (ends 32)
  // FFN set (attention buffers dead)
  u16* f1h = (u16*)(rA + 8 * MiB);      // 8 MiB (4096x1024)
  u16* f2h = (u16*)(rA + 16 * MiB);     // 8 MiB (1024x4096)
  u16* fth = (u16*)(rA + 24 * MiB);     // 16 MiB (2048x4096 hi)
  // vocab set
  u16* vh  = (u16*)(rA + 8 * MiB);      // 62.5 MiB (32000x1024), ends 70.5
  float* vpart = (float*)(rA + 71 * MiB); // 2 MiB (2048x256 row partials)
  u16* Qt = qkvT;
  u16* Kt = qkvT + 2097152;
  u16* Vt = qkvT + 2 * 2097152;

  const long DD = (long)DMODEL * DMODEL;
  const long DF = (long)DMODEL * DFFN;

  rope_tab_kernel<<<(SEQLEN * 32) / 256, 256, 0, stream>>>(cosT, sinT);

  auto attention = [&](int self, const float* Wq, const float* Bq,
                       const float* Wk, const float* Bk,
                       const float* Wv, const float* Bv,
                       const float* Wo, const float* Bo,
                       const int* tok, int causal) {
    wconv_attn_kernel<<<dim3(32, 16, 4), 256, 0, stream>>>(
        Wq, Wk, Wv, Wo, Bq, Bk, Bv, aWh, oWh, fusedB);
    if (self) {
      gemm_t_kernel<128, 64, 5, 2><<<dim3(16, 48), 256, 0, stream>>>(
          sth, aWh, fusedB, nullptr, nullptr, nullptr, qkvT, cosT, sinT,
          1024, 32, 32, 0, 0, 0);
    } else {
      gemm_t_kernel<64, 64, 5, 2><<<dim3(32, 16), 256, 0, stream>>>(
          sth, aWh, fusedB, nullptr, nullptr, nullptr, qkvT, cosT, sinT,
          1024, 32, 32, 0, 0, 0);
      gemm_t_kernel<128, 64, 5, 2><<<dim3(16, 32), 256, 0, stream>>>(
          mt, aWh + (long)64 * 32 * 512, fusedB, nullptr, nullptr, nullptr, qkvT, cosT, sinT,
          1024, 32, 32, 0, 0, 1024);
    }
    flash_kernel<<<dim3(8, 64), 256, 0, stream>>>(Qt, Kt, Vt, tok, ath, causal);
    gemm_t_kernel<64, 64, 0, 2><<<dim3(32, 16), 256, 0, stream>>>(
        ath, oWh, Bo, pb, nullptr, nullptr, nullptr, nullptr, nullptr,
        1024, 32, 32, 1024, 0, 0);
  };

  auto ffn = [&](const float* W1, const float* B1, const float* W2, const float* B2) {
    wconv_ffn_kernel<<<4096, 256, 0, stream>>>(W1, W2, f1h, f2h);
    gemm_t_kernel<128, 64, 3, 2><<<dim3(16, 64), 256, 0, stream>>>(
        sth, f1h, B1, nullptr, fth, nullptr, nullptr, nullptr, nullptr,
        1024, 32, 32, 0, 128, 0);
    gemm_t_kernel<64, 64, 0, 4><<<dim3(32, 16), 256, 0, stream>>>(
        fth, f2h, B2, pb, nullptr, nullptr, nullptr, nullptr, nullptr,
        4096, 128, 128, 1024, 0, 0);
  };

  // -------- encoder --------
  embed_t_kernel<<<MROWS, 256, 0, stream>>>(src, enc_emb, xb, sth);
  for (int l = 0; l < NLAYER; ++l) {
    attention(1, eWq + l * DD, eBq + l * DMODEL, eWk + l * DD, eBk + l * DMODEL,
              eWv + l * DD, eBv + l * DMODEL, eWo + l * DD, eBo + l * DMODEL, src, 0);
    ln_fused_kernel<<<MROWS, 256, 0, stream>>>(xb, pb, eL1g + l * DMODEL, eL1b + l * DMODEL,
                                               xb, sth);
    ffn(eF1 + l * DF, eF1b + l * DFFN, eF2 + l * DF, eF2b + l * DMODEL);
    ln_fused_kernel<<<MROWS, 256, 0, stream>>>(xb, pb, eL2g + l * DMODEL, eL2b + l * DMODEL,
                                               xb, (l == NLAYER - 1) ? mt : sth);
  }
  // -------- decoder --------
  embed_t_kernel<<<MROWS, 256, 0, stream>>>(tgt, dec_emb, yb, sth);
  for (int l = 0; l < NLAYER; ++l) {
    attention(1, dsWq + l * DD, dsBq + l * DMODEL, dsWk + l * DD, dsBk + l * DMODEL,
              dsWv + l * DD, dsBv + l * DMODEL, dsWo + l * DD, dsBo + l * DMODEL, tgt, 1);
    ln_fused_kernel<<<MROWS, 256, 0, stream>>>(yb, pb, dL1g + l * DMODEL, dL1b + l * DMODEL,
                                               yb, sth);
    attention(0, dcWq + l * DD, dcBq + l * DMODEL, dcWk + l * DD, dcBk + l * DMODEL,
              dcWv + l * DD, dcBv + l * DMODEL, dcWo + l * DD, dcBo + l * DMODEL, src, 0);
    ln_fused_kernel<<<MROWS, 256, 0, stream>>>(yb, pb, dL2g + l * DMODEL, dL2b + l * DMODEL,
                                               yb, sth);
    ffn(dF1 + l * DF, dF1b + l * DFFN, dF2 + l * DF, dF2b + l * DMODEL);
    ln_fused_kernel<<<MROWS, 256, 0, stream>>>(yb, pb, dL3g + l * DMODEL, dL3b + l * DMODEL,
                                               yb, sth);
  }
  // -------- final projection (exp fused, nt stores) + normalize --------
  float* outp = (float*)d_out;
  wconv_kernel<<<dim3(32, 500), 256, 0, stream>>>(fW, vh, 1024, VOCAB, 0);
  gemm_t_kernel<128, 128, 4, 2><<<dim3(16, 250), 256, 0, stream>>>(
      sth, vh, fb, outp, nullptr, vpart, nullptr, nullptr, nullptr,
      1024, 32, 32, VOCAB, 0, 0);
  vocab_norm_kernel<<<MROWS, 256, 0, stream>>>(outp, vpart);
}